// Round 1
// baseline (713.505 us; speedup 1.0000x reference)
//
#include <hip/hip_runtime.h>

typedef short bf16x8 __attribute__((ext_vector_type(8)));
typedef float f32x4 __attribute__((ext_vector_type(4)));
typedef unsigned short u16;

#define B_    32
#define N_    1025
#define H_    8
#define DH_   64
#define DIM_  512
#define M_    (B_*N_)      // 32800
#define NPAD_ 1056
#define SCALE_ 0.125f

__device__ __forceinline__ u16 f2bf(float f){
  unsigned u = __builtin_bit_cast(unsigned, f);
  u += 0x7FFFu + ((u >> 16) & 1u);
  return (u16)(u >> 16);
}
__device__ __forceinline__ float bf2f(u16 v){
  unsigned u = ((unsigned)v) << 16;
  return __builtin_bit_cast(float, u);
}

// ---------------- prep kernels ----------------
__global__ __launch_bounds__(256)
void k_conv_x(const float* __restrict__ x, u16* __restrict__ o, int n4){
  int i = blockIdx.x*256 + threadIdx.x;
  if (i >= n4) return;
  float4 v = ((const float4*)x)[i];
  ushort4 r;
  r.x = f2bf(v.x); r.y = f2bf(v.y); r.z = f2bf(v.z); r.w = f2bf(v.w);
  ((ushort4*)o)[i] = r;
}

// w: R x C row-major -> wt: C x R (bf16)
__global__ __launch_bounds__(256)
void k_transpose(const float* __restrict__ w, u16* __restrict__ wt, int R, int C){
  int i = blockIdx.x*256 + threadIdx.x;
  if (i >= R*C) return;
  int n = i / R, k = i - n*R;
  wt[i] = f2bf(w[k*C + n]);
}

__global__ __launch_bounds__(256)
void k_bias(const int* __restrict__ idx, const float* __restrict__ pe, u16* __restrict__ bh){
  int i = blockIdx.x*256 + threadIdx.x;   // 8 * 1024 * 1024
  int h = i >> 20, ij = i & 0xFFFFF;
  bh[i] = f2bf(pe[idx[ij]*H_ + h]);
}

// ---------------- QKV GEMM + fused RMSNorm / rearrange ----------------
// grid (513, 24); tile 64(M) x 64(N); N-tile == one (qkv_t, head) slice
__global__ __launch_bounds__(256)
void k_qkv(const u16* __restrict__ xb, const u16* __restrict__ wT, const float* __restrict__ g,
           u16* __restrict__ qn, u16* __restrict__ kn, u16* __restrict__ vT){
  __shared__ u16 As[64][40];
  __shared__ u16 Bs[64][40];
  __shared__ u16 Cs[64][66];
  const int tid = threadIdx.x;
  const int lane = tid & 63, wid = tid >> 6;
  const int lg = lane >> 4, lr = lane & 15;
  const int m0 = blockIdx.x * 64;
  const int nt = blockIdx.y;
  const int qkv_t = nt >> 3, h = nt & 7;
  const int n0 = nt * 64;
  const int srow = tid >> 2, sc8 = (tid & 3) * 8;

  f32x4 acc[4];
#pragma unroll
  for (int i=0;i<4;++i) acc[i] = {0.f,0.f,0.f,0.f};

  const int gm = m0 + srow;
  const u16* aptr = xb + (size_t)gm*DIM_ + sc8;
  const u16* bptr = wT + (size_t)(n0+srow)*DIM_ + sc8;
  for (int k0 = 0; k0 < DIM_; k0 += 32){
    bf16x8 av = {0,0,0,0,0,0,0,0};
    if (gm < M_) av = *(const bf16x8*)(aptr + k0);
    bf16x8 bv = *(const bf16x8*)(bptr + k0);
    *(bf16x8*)&As[srow][sc8] = av;
    *(bf16x8*)&Bs[srow][sc8] = bv;
    __syncthreads();
    bf16x8 af = *(const bf16x8*)&As[16*wid + lr][lg*8];
#pragma unroll
    for (int nf=0; nf<4; ++nf){
      bf16x8 bfv = *(const bf16x8*)&Bs[16*nf + lr][lg*8];
      acc[nf] = __builtin_amdgcn_mfma_f32_16x16x32_bf16(af, bfv, acc[nf], 0, 0, 0);
    }
    __syncthreads();
  }

  const int rowb = 16*wid + 4*lg;
  if (qkv_t < 2){
    float rstd[4];
#pragma unroll
    for (int r=0;r<4;++r){
      float s = 0.f;
#pragma unroll
      for (int nf=0;nf<4;++nf) s += acc[nf][r]*acc[nf][r];
      s += __shfl_xor(s, 1); s += __shfl_xor(s, 2);
      s += __shfl_xor(s, 4); s += __shfl_xor(s, 8);
      rstd[r] = rsqrtf(s*(1.f/64.f) + 1e-6f);
    }
    u16* dst = (qkv_t == 0) ? qn : kn;
#pragma unroll
    for (int nf=0;nf<4;++nf){
      int d = 16*nf + lr;
      float gv = g[d];
#pragma unroll
      for (int r=0;r<4;++r){
        int m = m0 + rowb + r;
        if (m < M_){
          int b = m / N_, n = m - b*N_;
          dst[(size_t)((b*H_ + h)*N_ + n)*64 + d] = f2bf(acc[nf][r]*rstd[r]*gv);
        }
      }
    }
  } else {
#pragma unroll
    for (int nf=0;nf<4;++nf)
#pragma unroll
      for (int r=0;r<4;++r)
        Cs[rowb + r][16*nf + lr] = f2bf(acc[nf][r]);
    __syncthreads();
    const int nl = tid & 63;
    const int db = tid >> 6;
    int m = m0 + nl;
    if (m < M_){
      int b = m / N_, n = m - b*N_;
      u16* vbase = vT + (size_t)((b*H_ + h)*64)*NPAD_ + n;
#pragma unroll
      for (int pass=0; pass<16; ++pass){
        int d = db + pass*4;
        vbase[(size_t)d*NPAD_] = Cs[nl][d];
      }
    }
  }
}

// ---------------- flash attention ----------------
// grid (17, 256): x = q-tile (64 rows), y = b*H + h. 4 waves x 16 rows.
__global__ __launch_bounds__(256)
void k_attn(const u16* __restrict__ qn, const u16* __restrict__ kn, const u16* __restrict__ vT,
            const u16* __restrict__ bh_tab, u16* __restrict__ ao){
  __shared__ u16 Qs[64][72];
  __shared__ u16 Ks[32][72];
  __shared__ u16 Vs[64][40];
  __shared__ u16 Ps[4][16][40];
  const int tid = threadIdx.x;
  const int lane = tid & 63, wid = tid >> 6;
  const int lg = lane >> 4, lr = lane & 15;
  const int q0 = blockIdx.x * 64;
  const int bh = blockIdx.y;
  const int h = bh & 7;
  const u16* qp = qn + (size_t)bh*N_*64;
  const u16* kp = kn + (size_t)bh*N_*64;
  const u16* vp = vT + (size_t)bh*64*NPAD_;
  const u16* bp = bh_tab + (size_t)h*1024*1024;

  {
    int row = tid >> 2, c16 = (tid & 3)*16;
    bf16x8 z = {0,0,0,0,0,0,0,0};
    bf16x8 v0 = z, v1 = z;
    if (q0 + row < N_){
      v0 = *(const bf16x8*)(qp + (size_t)(q0+row)*64 + c16);
      v1 = *(const bf16x8*)(qp + (size_t)(q0+row)*64 + c16 + 8);
    }
    *(bf16x8*)&Qs[row][c16]   = v0;
    *(bf16x8*)&Qs[row][c16+8] = v1;
  }
  __syncthreads();
  bf16x8 qf0 = *(const bf16x8*)&Qs[16*wid + lr][lg*8];
  bf16x8 qf1 = *(const bf16x8*)&Qs[16*wid + lr][32 + lg*8];

  float m_r[4], l_r[4];
  f32x4 o[4];
#pragma unroll
  for (int r=0;r<4;++r){ m_r[r] = -1e30f; l_r[r] = 0.f; }
#pragma unroll
  for (int d=0; d<4; ++d) o[d] = {0.f,0.f,0.f,0.f};

  const int krow = tid >> 3, kc8 = (tid & 7)*8;
  const int vrow = tid >> 2, vc8 = (tid & 3)*8;

  for (int t=0; t<33; ++t){
    const int kv0 = t*32;
    __syncthreads();
    {
      bf16x8 kvv = {0,0,0,0,0,0,0,0};
      if (kv0 + krow < N_) kvv = *(const bf16x8*)(kp + (size_t)(kv0+krow)*64 + kc8);
      *(bf16x8*)&Ks[krow][kc8] = kvv;
      bf16x8 vv = *(const bf16x8*)(vp + (size_t)vrow*NPAD_ + kv0 + vc8);
      *(bf16x8*)&Vs[vrow][vc8] = vv;
    }
    __syncthreads();

    f32x4 s0 = {0.f,0.f,0.f,0.f}, s1 = {0.f,0.f,0.f,0.f};
    {
      bf16x8 b00 = *(const bf16x8*)&Ks[lr][lg*8];
      bf16x8 b01 = *(const bf16x8*)&Ks[lr][32 + lg*8];
      bf16x8 b10 = *(const bf16x8*)&Ks[16 + lr][lg*8];
      bf16x8 b11 = *(const bf16x8*)&Ks[16 + lr][32 + lg*8];
      s0 = __builtin_amdgcn_mfma_f32_16x16x32_bf16(qf0, b00, s0, 0,0,0);
      s0 = __builtin_amdgcn_mfma_f32_16x16x32_bf16(qf1, b01, s0, 0,0,0);
      s1 = __builtin_amdgcn_mfma_f32_16x16x32_bf16(qf0, b10, s1, 0,0,0);
      s1 = __builtin_amdgcn_mfma_f32_16x16x32_bf16(qf1, b11, s1, 0,0,0);
    }

    float sv[2][4];
    const int irow = q0 + 16*wid + 4*lg;
#pragma unroll
    for (int nf=0; nf<2; ++nf){
      int j = kv0 + 16*nf + lr;
#pragma unroll
      for (int r=0;r<4;++r){
        float xx = (nf==0 ? s0[r] : s1[r]) * SCALE_;
        int i = irow + r;
        if (j < N_){
          if (i >= 1 && i < N_ && j >= 1)
            xx += bf2f(bp[(size_t)(i-1)*1024 + (j-1)]);
        } else xx = -1e30f;
        sv[nf][r] = xx;
      }
    }

    float p[2][4], mn[4], sc[4];
#pragma unroll
    for (int r=0;r<4;++r){
      float mx = fmaxf(sv[0][r], sv[1][r]);
      mx = fmaxf(mx, __shfl_xor(mx, 1));
      mx = fmaxf(mx, __shfl_xor(mx, 2));
      mx = fmaxf(mx, __shfl_xor(mx, 4));
      mx = fmaxf(mx, __shfl_xor(mx, 8));
      mn[r] = fmaxf(m_r[r], mx);
      sc[r] = __expf(m_r[r] - mn[r]);
      m_r[r] = mn[r];
    }
#pragma unroll
    for (int nf=0;nf<2;++nf)
#pragma unroll
      for (int r=0;r<4;++r) p[nf][r] = __expf(sv[nf][r] - mn[r]);
#pragma unroll
    for (int r=0;r<4;++r){
      float su = p[0][r] + p[1][r];
      su += __shfl_xor(su, 1); su += __shfl_xor(su, 2);
      su += __shfl_xor(su, 4); su += __shfl_xor(su, 8);
      l_r[r] = l_r[r]*sc[r] + su;
    }
#pragma unroll
    for (int d=0; d<4; ++d)
#pragma unroll
      for (int r=0;r<4;++r) o[d][r] *= sc[r];

#pragma unroll
    for (int nf=0;nf<2;++nf)
#pragma unroll
      for (int r=0;r<4;++r)
        Ps[wid][4*lg + r][16*nf + lr] = f2bf(p[nf][r]);
    bf16x8 pf = *(const bf16x8*)&Ps[wid][lr][lg*8];
#pragma unroll
    for (int d=0; d<4; ++d){
      bf16x8 bv = *(const bf16x8*)&Vs[16*d + lr][lg*8];
      o[d] = __builtin_amdgcn_mfma_f32_16x16x32_bf16(pf, bv, o[d], 0,0,0);
    }
  }

  const int b = bh >> 3;
#pragma unroll
  for (int r=0;r<4;++r){
    int i = q0 + 16*wid + 4*lg + r;
    if (i < N_){
      float inv = 1.f / l_r[r];
#pragma unroll
      for (int d=0; d<4; ++d){
        int dd = 16*d + lr;
        ao[(size_t)(b*N_ + i)*DIM_ + h*64 + dd] = f2bf(o[d][r]*inv);
      }
    }
  }
}

// ---------------- output projection ----------------
// grid (513, 8); tile 64 x 64
__global__ __launch_bounds__(256)
void k_oproj(const u16* __restrict__ ab, const u16* __restrict__ wT, const float* __restrict__ bo,
             float* __restrict__ out){
  __shared__ u16 As[64][40];
  __shared__ u16 Bs[64][40];
  const int tid = threadIdx.x;
  const int lane = tid & 63, wid = tid >> 6;
  const int lg = lane >> 4, lr = lane & 15;
  const int m0 = blockIdx.x * 64;
  const int n0 = blockIdx.y * 64;
  const int srow = tid >> 2, sc8 = (tid & 3) * 8;

  f32x4 acc[4];
#pragma unroll
  for (int i=0;i<4;++i) acc[i] = {0.f,0.f,0.f,0.f};

  const int gm = m0 + srow;
  const u16* aptr = ab + (size_t)gm*DIM_ + sc8;
  const u16* bptr = wT + (size_t)(n0+srow)*DIM_ + sc8;
  for (int k0 = 0; k0 < DIM_; k0 += 32){
    bf16x8 av = {0,0,0,0,0,0,0,0};
    if (gm < M_) av = *(const bf16x8*)(aptr + k0);
    bf16x8 bv = *(const bf16x8*)(bptr + k0);
    *(bf16x8*)&As[srow][sc8] = av;
    *(bf16x8*)&Bs[srow][sc8] = bv;
    __syncthreads();
    bf16x8 af = *(const bf16x8*)&As[16*wid + lr][lg*8];
#pragma unroll
    for (int nf=0; nf<4; ++nf){
      bf16x8 bfv = *(const bf16x8*)&Bs[16*nf + lr][lg*8];
      acc[nf] = __builtin_amdgcn_mfma_f32_16x16x32_bf16(af, bfv, acc[nf], 0, 0, 0);
    }
    __syncthreads();
  }
  const int rowb = 16*wid + 4*lg;
#pragma unroll
  for (int nf=0;nf<4;++nf){
    int nc = n0 + 16*nf + lr;
    float bb = bo[nc];
#pragma unroll
    for (int r=0;r<4;++r){
      int m = m0 + rowb + r;
      if (m < M_) out[(size_t)m*DIM_ + nc] = acc[nf][r] + bb;
    }
  }
}

// ---------------- launch ----------------
extern "C" void kernel_launch(void* const* d_in, const int* in_sizes, int n_in,
                              void* d_out, int out_size, void* d_ws, size_t ws_size,
                              hipStream_t stream) {
  const float* x     = (const float*)d_in[0];
  const float* w_qkv = (const float*)d_in[1];
  const float* g     = (const float*)d_in[2];
  const float* pe    = (const float*)d_in[3];
  const float* w_out = (const float*)d_in[4];
  const float* b_out = (const float*)d_in[5];
  const int*   bidx  = (const int*)d_in[6];
  float* out = (float*)d_out;

  char* ws = (char*)d_ws;
  u16* xb    = (u16*)(ws);                          // 33,587,200 B
  u16* wT    = (u16*)(ws + 33587200);               //  1,572,864 B
  u16* woT   = (u16*)(ws + 35160064);               //    524,288 B
  u16* qnb   = (u16*)(ws + 35684352);               // 33,587,200 B
  u16* knb   = (u16*)(ws + 69271552);               // 33,587,200 B
  u16* vTb   = (u16*)(ws + 102858752);              // 34,603,008 B
  u16* biash = (u16*)(ws + 137461760);              // 16,777,216 B
  u16* aob   = (u16*)(ws + 154238976);              // 33,587,200 B  (total 187,826,176)

  int n4 = (B_*N_*DIM_)/4;
  k_conv_x<<<(n4+255)/256, 256, 0, stream>>>(x, xb, n4);
  k_transpose<<<(1536*512+255)/256, 256, 0, stream>>>(w_qkv, wT, 512, 1536);
  k_transpose<<<(512*512+255)/256, 256, 0, stream>>>(w_out, woT, 512, 512);
  k_bias<<<(8*1024*1024)/256, 256, 0, stream>>>(bidx, pe, biash);

  dim3 gq(513, 24);
  k_qkv<<<gq, 256, 0, stream>>>(xb, wT, g, qnb, knb, vTb);
  dim3 ga(17, 256);
  k_attn<<<ga, 256, 0, stream>>>(qnb, knb, vTb, biash, aob);
  dim3 go(513, 8);
  k_oproj<<<go, 256, 0, stream>>>(aob, woT, b_out, out);
}

// Round 2
// 397.609 us; speedup vs baseline: 1.7945x; 1.7945x over previous
//
#include <hip/hip_runtime.h>

typedef short bf16x8 __attribute__((ext_vector_type(8)));
typedef float f32x4 __attribute__((ext_vector_type(4)));
typedef float f32x16 __attribute__((ext_vector_type(16)));
typedef unsigned int u32;
typedef u32 u32x4 __attribute__((ext_vector_type(4)));
typedef unsigned short u16;

#define B_    32
#define N_    1025
#define H_    8
#define DIM_  512
#define M_    (B_*N_)      // 32800
#define QP_   1152         // qn row pitch per bh
#define KP_   1056         // kn rows per bh
#define VP_   1056         // vT col pitch
#define BIP_  1152         // bias_r i pitch
#define SCALE_ 0.125f

__device__ __forceinline__ u16 f2bf(float f){
  unsigned u = __builtin_bit_cast(unsigned, f);
  u += 0x7FFFu + ((u >> 16) & 1u);
  return (u16)(u >> 16);
}
__device__ __forceinline__ float bf2f(u16 v){
  unsigned u = ((unsigned)v) << 16;
  return __builtin_bit_cast(float, u);
}
__device__ __forceinline__ u32 cvtpk(float a, float b){
  u32 r;
  asm("v_cvt_pk_bf16_f32 %0, %1, %2" : "=v"(r) : "v"(a), "v"(b));
  return r;
}
__device__ __forceinline__ void pswap(u32 &a, u32 &b){
  asm("v_permlane32_swap_b32 %0, %1" : "+v"(a), "+v"(b));
}
__device__ __forceinline__ void gll16(const u16* g, u16* l){
  __builtin_amdgcn_global_load_lds((const __attribute__((address_space(1))) u16*)(g),
                                   (__attribute__((address_space(3))) u16*)(l), 16, 0, 0);
}

// ---------------- prep kernels ----------------
__global__ __launch_bounds__(256)
void k_conv_x(const float* __restrict__ x, u16* __restrict__ o, int n4){
  int i = blockIdx.x*256 + threadIdx.x;
  if (i >= n4) return;
  float4 v = ((const float4*)x)[i];
  ushort4 r;
  r.x = f2bf(v.x); r.y = f2bf(v.y); r.z = f2bf(v.z); r.w = f2bf(v.w);
  ((ushort4*)o)[i] = r;
}

__global__ __launch_bounds__(256)
void k_transpose(const float* __restrict__ w, u16* __restrict__ wt, int R, int C){
  int i = blockIdx.x*256 + threadIdx.x;
  if (i >= R*C) return;
  int n = i / R, k = i - n*R;
  wt[i] = f2bf(w[k*C + n]);
}

// bias_r[h][jt(33)][i(1152)][hi(2)][16 regs], values in C/D reg order; masked.
__global__ __launch_bounds__(256)
void k_biasr(const int* __restrict__ idx, const float* __restrict__ pe, u16* __restrict__ br){
  int i_lin = blockIdx.x*256 + threadIdx.x;  // 8*33*1152*32 total
  int v = i_lin & 15, hi = (i_lin>>4)&1;
  int t1 = i_lin >> 5;
  int i = t1 % 1152;
  int t2 = t1 / 1152;
  int tj = t2 % 33;
  int h = t2 / 33;
  int j = tj*32 + (v&3) + 8*(v>>2) + 4*hi;
  float val;
  if (j >= 1 && j <= 1024 && i >= 1 && i <= 1024)
    val = pe[idx[(i-1)*1024 + (j-1)]*8 + h];
  else
    val = (j <= 1024) ? 0.f : -1e9f;
  br[i_lin] = f2bf(val);
}

// zero tails: qn rows [1025,1152), kn rows [1025,1056), vT cols [1025,1056)
__global__ __launch_bounds__(256)
void k_ztail(u16* __restrict__ qn, u16* __restrict__ kn, u16* __restrict__ vT){
  int i = blockIdx.x*256 + threadIdx.x;
  if (i < 2080768){
    int bh = i / (127*64); int r = i - bh*(127*64);
    qn[((size_t)bh*QP_ + 1025 + (r>>6))*64 + (r&63)] = 0;
  } else if (i < 2588672){
    int k = i - 2080768; int bh = k/(31*64); int r = k - bh*(31*64);
    kn[((size_t)bh*KP_ + 1025 + (r>>6))*64 + (r&63)] = 0;
  } else if (i < 3096576){
    int k = i - 2588672; int bh = k/(64*31); int r = k - bh*(64*31);
    int d = r/31, c = r - d*31;
    vT[((size_t)bh*64 + d)*VP_ + 1025 + c] = 0;
  }
}

// ---------------- QKV GEMM + fused RMSNorm / rearrange ----------------
__global__ __launch_bounds__(256)
void k_qkv(const u16* __restrict__ xb, const u16* __restrict__ wT, const float* __restrict__ g,
           u16* __restrict__ qn, u16* __restrict__ kn, u16* __restrict__ vT){
  __shared__ u16 As[64][40];
  __shared__ u16 Bs[64][40];
  __shared__ u16 Cs[64][66];
  const int tid = threadIdx.x;
  const int lane = tid & 63, wid = tid >> 6;
  const int lg = lane >> 4, lr = lane & 15;
  const int m0 = blockIdx.x * 64;
  const int nt = blockIdx.y;
  const int qkv_t = nt >> 3, h = nt & 7;
  const int n0 = nt * 64;
  const int srow = tid >> 2, sc8 = (tid & 3) * 8;

  f32x4 acc[4];
#pragma unroll
  for (int i=0;i<4;++i) acc[i] = {0.f,0.f,0.f,0.f};

  const int gm = m0 + srow;
  const u16* aptr = xb + (size_t)gm*DIM_ + sc8;
  const u16* bptr = wT + (size_t)(n0+srow)*DIM_ + sc8;
  for (int k0 = 0; k0 < DIM_; k0 += 32){
    bf16x8 av = {0,0,0,0,0,0,0,0};
    if (gm < M_) av = *(const bf16x8*)(aptr + k0);
    bf16x8 bv = *(const bf16x8*)(bptr + k0);
    *(bf16x8*)&As[srow][sc8] = av;
    *(bf16x8*)&Bs[srow][sc8] = bv;
    __syncthreads();
    bf16x8 af = *(const bf16x8*)&As[16*wid + lr][lg*8];
#pragma unroll
    for (int nf=0; nf<4; ++nf){
      bf16x8 bfv = *(const bf16x8*)&Bs[16*nf + lr][lg*8];
      acc[nf] = __builtin_amdgcn_mfma_f32_16x16x32_bf16(af, bfv, acc[nf], 0, 0, 0);
    }
    __syncthreads();
  }

  const int rowb = 16*wid + 4*lg;
  if (qkv_t < 2){
    float rstd[4];
#pragma unroll
    for (int r=0;r<4;++r){
      float s = 0.f;
#pragma unroll
      for (int nf=0;nf<4;++nf) s += acc[nf][r]*acc[nf][r];
      s += __shfl_xor(s, 1); s += __shfl_xor(s, 2);
      s += __shfl_xor(s, 4); s += __shfl_xor(s, 8);
      rstd[r] = rsqrtf(s*(1.f/64.f) + 1e-6f);
    }
    u16* dst = (qkv_t == 0) ? qn : kn;
    const size_t pitch = (qkv_t == 0) ? QP_ : KP_;
    const float extra = (qkv_t == 0) ? SCALE_ : 1.f;
#pragma unroll
    for (int nf=0;nf<4;++nf){
      int d = 16*nf + lr;
      float gv = g[d] * extra;
#pragma unroll
      for (int r=0;r<4;++r){
        int m = m0 + rowb + r;
        if (m < M_){
          int b = m / N_, n = m - b*N_;
          dst[((size_t)(b*H_ + h)*pitch + n)*64 + d] = f2bf(acc[nf][r]*rstd[r]*gv);
        }
      }
    }
  } else {
#pragma unroll
    for (int nf=0;nf<4;++nf)
#pragma unroll
      for (int r=0;r<4;++r)
        Cs[rowb + r][16*nf + lr] = f2bf(acc[nf][r]);
    __syncthreads();
    const int nl = tid & 63;
    const int db = tid >> 6;
    int m = m0 + nl;
    if (m < M_){
      int b = m / N_, n = m - b*N_;
      u16* vbase = vT + (size_t)((b*H_ + h)*64)*VP_ + n;
#pragma unroll
      for (int pass=0; pass<16; ++pass){
        int d = db + pass*4;
        vbase[(size_t)d*VP_] = Cs[nl][d];
      }
    }
  }
}

// ---------------- flash attention, 32x32 swapped-operand ----------------
// grid 2304 = 8 XCD-chunks x (32 b x 9 qt); 4 waves x 32 q-rows = 128-row q-block
__global__ __launch_bounds__(256)
void k_attn2(const u16* __restrict__ qn, const u16* __restrict__ kn, const u16* __restrict__ vT,
             const u16* __restrict__ br, u16* __restrict__ ao){
  __shared__ u16 Ks[2][2048];
  __shared__ u16 Vs[2][2048];
  const int tid = threadIdx.x;
  const int lane = tid & 63, wave = tid >> 6;
  const int il = lane & 31, hi = lane >> 5;
  int wg = ((blockIdx.x & 7) * 288) + (blockIdx.x >> 3);
  int h = wg / 288;
  int rem = wg - h*288;
  int b = rem / 9, qt = rem - (rem/9)*9;
  int bh = b*8 + h;
  int i0 = qt*128 + wave*32;

  // Q fragments (hoisted; q pre-scaled by SCALE in k_qkv)
  const u16* qp = qn + ((size_t)bh*QP_ + (i0 + il))*64 + hi*8;
  bf16x8 qf[4];
#pragma unroll
  for (int c=0;c<4;++c) qf[c] = *(const bf16x8*)(qp + 16*c);

  // staging: K tile 32x64 (swizzle chunk^=(j&7)); V tile 64x32 (chunk^=((d>>1)&3))
  const int kj = tid >> 3, kc = tid & 7;
  const u16* ksrc = kn + ((size_t)bh*KP_ + kj)*64 + ((kc ^ (kj & 7))*8);
  const int vd = tid >> 2, vc = tid & 3;
  const u16* vsrc = vT + ((size_t)bh*64 + vd)*VP_ + ((vc ^ ((vd>>1)&3))*8);
  u16* kldsb0 = &Ks[0][0] + wave*512;
  u16* vldsb0 = &Vs[0][0] + wave*512;
  u16* kldsb1 = &Ks[1][0] + wave*512;
  u16* vldsb1 = &Vs[1][0] + wave*512;

  gll16(ksrc, kldsb0);
  gll16(vsrc, vldsb0);

  float m = -1e30f, lsum = 0.f;
  f32x16 oA, oB;
#pragma unroll
  for (int r=0;r<16;++r){ oA[r]=0.f; oB[r]=0.f; }

  const u16* bptr = br + (((size_t)(h*33))*BIP_ + (i0 + il))*32 + hi*16;

  for (int t=0; t<33; ++t){
    const int cur = t & 1;
    __syncthreads();
    if (t < 32){
      gll16(ksrc + (size_t)(t+1)*32*64, cur ? kldsb0 : kldsb1);
      gll16(vsrc + (t+1)*32,            cur ? vldsb0 : vldsb1);
    }
    bf16x8 b0 = *(const bf16x8*)(bptr);
    bf16x8 b1 = *(const bf16x8*)(bptr + 8);
    bptr += (size_t)BIP_*32;

    // QK^T (swapped): S^T[j][i], lane holds q-row i=il, 16 j's
    f32x16 s;
#pragma unroll
    for (int r=0;r<16;++r) s[r] = 0.f;
#pragma unroll
    for (int c=0;c<4;++c){
      int ko = il*64 + (((2*c + hi) ^ (il & 7))*8);
      bf16x8 kf = *(const bf16x8*)(&Ks[cur][0] + ko);
      s = __builtin_amdgcn_mfma_f32_32x32x16_bf16(kf, qf[c], s, 0, 0, 0);
    }
    // bias add (pre-masked, reg-ordered)
#pragma unroll
    for (int r=0;r<16;++r){
      u16 bv = (r < 8) ? ((u16)b0[r]) : ((u16)b1[r-8]);
      s[r] += bf2f(bv);
    }
    // row max: 15 in-lane + 1 cross-half
    float pm = fmaxf(
      fmaxf(fmaxf(fmaxf(s[0],s[1]),fmaxf(s[2],s[3])), fmaxf(fmaxf(s[4],s[5]),fmaxf(s[6],s[7]))),
      fmaxf(fmaxf(fmaxf(s[8],s[9]),fmaxf(s[10],s[11])), fmaxf(fmaxf(s[12],s[13]),fmaxf(s[14],s[15]))));
    pm = fmaxf(pm, __shfl_xor(pm, 32));
    if (__any(pm > m + 8.f)){
      float mnew = fmaxf(m, pm);
      float sc = __expf(m - mnew);
#pragma unroll
      for (int r=0;r<16;++r){ oA[r] *= sc; oB[r] *= sc; }
      lsum *= sc; m = mnew;
    }
    f32x16 p;
#pragma unroll
    for (int r=0;r<16;++r) p[r] = __expf(s[r] - m);
    float su = ((p[0]+p[1])+(p[2]+p[3])) + ((p[4]+p[5])+(p[6]+p[7]))
             + ((p[8]+p[9])+(p[10]+p[11])) + ((p[12]+p[13])+(p[14]+p[15]));
    su += __shfl_xor(su, 32);
    lsum += su;

    // pack P^T fragments: cvt_pk + permlane32_swap
    u32 X0 = cvtpk(p[0],p[1]),  X1 = cvtpk(p[2],p[3]);
    u32 Y0 = cvtpk(p[4],p[5]),  Y1 = cvtpk(p[6],p[7]);
    u32 X2 = cvtpk(p[8],p[9]),  X3 = cvtpk(p[10],p[11]);
    u32 Y2 = cvtpk(p[12],p[13]), Y3 = cvtpk(p[14],p[15]);
    pswap(X0, Y0); pswap(X1, Y1); pswap(X2, Y2); pswap(X3, Y3);
    u32x4 w0 = {X0, X1, Y0, Y1};
    u32x4 w1 = {X2, X3, Y2, Y3};
    bf16x8 pv0 = __builtin_bit_cast(bf16x8, w0);
    bf16x8 pv1 = __builtin_bit_cast(bf16x8, w1);

    // PV: O^T = V^T * P^T
#pragma unroll
    for (int c2=0;c2<2;++c2){
      bf16x8 pv = c2 ? pv1 : pv0;
      int swz = ((2*c2 + hi) ^ ((il>>1)&3))*8;
      bf16x8 vfA = *(const bf16x8*)(&Vs[cur][0] + il*32 + swz);
      bf16x8 vfB = *(const bf16x8*)(&Vs[cur][0] + (32+il)*32 + swz);
      oA = __builtin_amdgcn_mfma_f32_32x32x16_bf16(vfA, pv, oA, 0, 0, 0);
      oB = __builtin_amdgcn_mfma_f32_32x32x16_bf16(vfB, pv, oB, 0, 0, 0);
    }
  }

  int i = i0 + il;
  if (i < N_){
    float inv = 1.f / lsum;
    u16* op = ao + ((size_t)(b*N_ + i))*DIM_ + h*64;
#pragma unroll
    for (int q=0;q<4;++q)
#pragma unroll
      for (int pr=0;pr<2;++pr){
        int d0 = 8*q + 4*hi + 2*pr;
        u32 wA = cvtpk(oA[4*q+2*pr]*inv, oA[4*q+2*pr+1]*inv);
        u32 wB = cvtpk(oB[4*q+2*pr]*inv, oB[4*q+2*pr+1]*inv);
        *(u32*)(op + d0) = wA;
        *(u32*)(op + 32 + d0) = wB;
      }
  }
}

// ---------------- output projection ----------------
__global__ __launch_bounds__(256)
void k_oproj(const u16* __restrict__ ab, const u16* __restrict__ wT, const float* __restrict__ bo,
             float* __restrict__ out){
  __shared__ u16 As[64][40];
  __shared__ u16 Bs[64][40];
  const int tid = threadIdx.x;
  const int lane = tid & 63, wid = tid >> 6;
  const int lg = lane >> 4, lr = lane & 15;
  const int m0 = blockIdx.x * 64;
  const int n0 = blockIdx.y * 64;
  const int srow = tid >> 2, sc8 = (tid & 3) * 8;

  f32x4 acc[4];
#pragma unroll
  for (int i=0;i<4;++i) acc[i] = {0.f,0.f,0.f,0.f};

  const int gm = m0 + srow;
  const u16* aptr = ab + (size_t)gm*DIM_ + sc8;
  const u16* bptr = wT + (size_t)(n0+srow)*DIM_ + sc8;
  for (int k0 = 0; k0 < DIM_; k0 += 32){
    bf16x8 av = {0,0,0,0,0,0,0,0};
    if (gm < M_) av = *(const bf16x8*)(aptr + k0);
    bf16x8 bv = *(const bf16x8*)(bptr + k0);
    *(bf16x8*)&As[srow][sc8] = av;
    *(bf16x8*)&Bs[srow][sc8] = bv;
    __syncthreads();
    bf16x8 af = *(const bf16x8*)&As[16*wid + lr][lg*8];
#pragma unroll
    for (int nf=0; nf<4; ++nf){
      bf16x8 bfv = *(const bf16x8*)&Bs[16*nf + lr][lg*8];
      acc[nf] = __builtin_amdgcn_mfma_f32_16x16x32_bf16(af, bfv, acc[nf], 0, 0, 0);
    }
    __syncthreads();
  }
  const int rowb = 16*wid + 4*lg;
#pragma unroll
  for (int nf=0;nf<4;++nf){
    int nc = n0 + 16*nf + lr;
    float bb = bo[nc];
#pragma unroll
    for (int r=0;r<4;++r){
      int m = m0 + rowb + r;
      if (m < M_) out[(size_t)m*DIM_ + nc] = acc[nf][r] + bb;
    }
  }
}

// ---------------- launch ----------------
extern "C" void kernel_launch(void* const* d_in, const int* in_sizes, int n_in,
                              void* d_out, int out_size, void* d_ws, size_t ws_size,
                              hipStream_t stream) {
  const float* x     = (const float*)d_in[0];
  const float* w_qkv = (const float*)d_in[1];
  const float* g     = (const float*)d_in[2];
  const float* pe    = (const float*)d_in[3];
  const float* w_out = (const float*)d_in[4];
  const float* b_out = (const float*)d_in[5];
  const int*   bidx  = (const int*)d_in[6];
  float* out = (float*)d_out;

  char* ws = (char*)d_ws;
  u16* xb    = (u16*)(ws);                    // 33,587,200  (aliased: aob reuses after k_qkv)
  u16* wT    = (u16*)(ws + 33587200);         //  1,572,864
  u16* woT   = (u16*)(ws + 35160064);         //    524,288
  u16* qnb   = (u16*)(ws + 35684352);         // 37,748,736
  u16* knb   = (u16*)(ws + 73433088);         // 34,603,008
  u16* vTb   = (u16*)(ws + 108036096);        // 34,603,008
  u16* biasr = (u16*)(ws + 142639104);        // 19,464,192  (end 162,103,296)
  u16* aob   = xb;                            // alias: xb dead after k_qkv

  int n4 = (B_*N_*DIM_)/4;
  k_conv_x<<<(n4+255)/256, 256, 0, stream>>>(x, xb, n4);
  k_transpose<<<(1536*512+255)/256, 256, 0, stream>>>(w_qkv, wT, 512, 1536);
  k_transpose<<<(512*512+255)/256, 256, 0, stream>>>(w_out, woT, 512, 512);
  k_biasr<<<38016, 256, 0, stream>>>(bidx, pe, biasr);
  k_ztail<<<12096, 256, 0, stream>>>(qnb, knb, vTb);

  dim3 gq(513, 24);
  k_qkv<<<gq, 256, 0, stream>>>(xb, wT, g, qnb, knb, vTb);
  k_attn2<<<2304, 256, 0, stream>>>(qnb, knb, vTb, biasr, aob);
  dim3 go(513, 8);
  k_oproj<<<go, 256, 0, stream>>>(aob, woT, b_out, out);
}

// Round 3
// 386.353 us; speedup vs baseline: 1.8468x; 1.0291x over previous
//
#include <hip/hip_runtime.h>

typedef short bf16x8 __attribute__((ext_vector_type(8)));
typedef float f32x4 __attribute__((ext_vector_type(4)));
typedef float f32x16 __attribute__((ext_vector_type(16)));
typedef unsigned int u32;
typedef u32 u32x4 __attribute__((ext_vector_type(4)));
typedef unsigned short u16;

#define B_    32
#define N_    1025
#define H_    8
#define DIM_  512
#define M_    (B_*N_)      // 32800
#define QP_   1152         // qn row pitch per bh
#define BIP_  1152         // bias_r i pitch
#define KVSZ_ 67584        // per-bh u16 size of kn2/v2 (33 tiles * 2048)
#define SCALE_ 0.125f
#define LOG2E_ 1.4426950408889634f
#define COFF_  12.0f       // fixed softmax offset (max |s*log2e| < 11.8)

__device__ __forceinline__ u16 f2bf(float f){
  unsigned u = __builtin_bit_cast(unsigned, f);
  u += 0x7FFFu + ((u >> 16) & 1u);
  return (u16)(u >> 16);
}
__device__ __forceinline__ u32 cvtpk(float a, float b){
  u32 r;
  asm("v_cvt_pk_bf16_f32 %0, %1, %2" : "=v"(r) : "v"(a), "v"(b));
  return r;
}
__device__ __forceinline__ void pswap(u32 &a, u32 &b){
  asm("v_permlane32_swap_b32 %0, %1" : "+v"(a), "+v"(b));
}
__device__ __forceinline__ void gll16(const u16* g, u16* l){
  __builtin_amdgcn_global_load_lds((const __attribute__((address_space(1))) u16*)(g),
                                   (__attribute__((address_space(3))) u16*)(l), 16, 0, 0);
}

// ---------------- prep kernels ----------------
__global__ __launch_bounds__(256)
void k_conv_x(const float* __restrict__ x, u16* __restrict__ o, int n4){
  int i = blockIdx.x*256 + threadIdx.x;
  if (i >= n4) return;
  float4 v = ((const float4*)x)[i];
  ushort4 r;
  r.x = f2bf(v.x); r.y = f2bf(v.y); r.z = f2bf(v.z); r.w = f2bf(v.w);
  ((ushort4*)o)[i] = r;
}

__global__ __launch_bounds__(256)
void k_transpose(const float* __restrict__ w, u16* __restrict__ wt, int R, int C){
  int i = blockIdx.x*256 + threadIdx.x;
  if (i >= R*C) return;
  int n = i / R, k = i - n*R;
  wt[i] = f2bf(w[k*C + n]);
}

// bias_r[h][jt(33)][i(1152)][hi(2)][16 regs]; value = pe*log2e - COFF (masked)
__global__ __launch_bounds__(256)
void k_biasr(const int* __restrict__ idx, const float* __restrict__ pe, u16* __restrict__ br){
  int i_lin = blockIdx.x*256 + threadIdx.x;  // 8*33*1152*32 total
  int v = i_lin & 15, hi = (i_lin>>4)&1;
  int t1 = i_lin >> 5;
  int i = t1 % 1152;
  int t2 = t1 / 1152;
  int tj = t2 % 33;
  int h = t2 / 33;
  int j = tj*32 + (v&3) + 8*(v>>2) + 4*hi;
  float val;
  if (j >= 1 && j <= 1024 && i >= 1 && i <= 1024)
    val = pe[idx[(i-1)*1024 + (j-1)]*8 + h] * LOG2E_ - COFF_;
  else
    val = (j <= 1024) ? -COFF_ : -1e9f;
  br[i_lin] = f2bf(val);
}

// zero tails: qn rows [1025,1152); kn2 tile-32 j in [1,32); v2 tile-32 j in [1,32)
__global__ __launch_bounds__(256)
void k_ztail(u16* __restrict__ qn, u16* __restrict__ kn2, u16* __restrict__ v2){
  int i = blockIdx.x*256 + threadIdx.x;
  if (i < 2080768){
    int bh = i / (127*64); int r = i - bh*(127*64);
    qn[((size_t)bh*QP_ + 1025 + (r>>6))*64 + (r&63)] = 0;
  } else if (i < 2588672){
    int k = i - 2080768; int bh = k/1984; int r = k - bh*1984;
    int n = 1025 + (r>>6), d = r & 63;
    kn2[(size_t)bh*KVSZ_ + 65536 + ((d>>3)<<8) + ((n&31)<<3) + (d&7)] = 0;
  } else if (i < 3096576){
    int k = i - 2588672; int bh = k/1984; int r = k - bh*1984;
    int n = 1025 + (r>>6), d = r & 63;
    v2[(size_t)bh*KVSZ_ + 65536 + (((n>>3)&3)<<9) + (d<<3) + (n&7)] = 0;
  }
}

// ---------------- QKV GEMM + fused RMSNorm / rearrange ----------------
// grid (513, 24); tile 64(M) x 64(N); N-tile == one (qkv_t, head) slice
__global__ __launch_bounds__(256)
void k_qkv(const u16* __restrict__ xb, const u16* __restrict__ wT, const float* __restrict__ g,
           u16* __restrict__ qn, u16* __restrict__ kn2, u16* __restrict__ v2){
  __shared__ u16 As[2][2048];
  __shared__ u16 Bs[2][2048];
  __shared__ u16 Cs[64][66];
  const int tid = threadIdx.x;
  const int lane = tid & 63, wid = tid >> 6;
  const int lg = lane >> 4, lr = lane & 15;
  const int m0 = blockIdx.x * 64;
  const int nt = blockIdx.y;
  const int qkv_t = nt >> 3, h = nt & 7;
  const int n0 = nt * 64;

  // staging: dest slot tid -> (row = tid>>2, chunkpos = tid&3); source chunk = pos ^ ((row>>1)&3)
  const int srow = tid >> 2;
  const int schunk = (tid & 3) ^ ((tid >> 3) & 3);
  const u16* asrc = xb + (size_t)(m0 + srow)*DIM_ + schunk*8;
  const u16* bsrc = wT + (size_t)(n0 + srow)*DIM_ + schunk*8;
  const int rsw = (lg ^ ((lr>>1)&3)) << 3;   // swizzled chunk byte offset for reads

  f32x4 acc[4];
#pragma unroll
  for (int i=0;i<4;++i) acc[i] = {0.f,0.f,0.f,0.f};

  gll16(asrc, &As[0][wid*512]);
  gll16(bsrc, &Bs[0][wid*512]);

  for (int s=0; s<16; ++s){
    const int cur = s & 1;
    __syncthreads();
    if (s < 15){
      gll16(asrc + (s+1)*32, &As[cur^1][wid*512]);
      gll16(bsrc + (s+1)*32, &Bs[cur^1][wid*512]);
    }
    bf16x8 af = *(const bf16x8*)&As[cur][(16*wid + lr)*32 + rsw];
#pragma unroll
    for (int nf=0; nf<4; ++nf){
      bf16x8 bfv = *(const bf16x8*)&Bs[cur][(16*nf + lr)*32 + rsw];
      acc[nf] = __builtin_amdgcn_mfma_f32_16x16x32_bf16(af, bfv, acc[nf], 0, 0, 0);
    }
  }

  const int rowb = 16*wid + 4*lg;
  if (qkv_t < 2){
    float rstd[4];
#pragma unroll
    for (int r=0;r<4;++r){
      float s = 0.f;
#pragma unroll
      for (int nf=0;nf<4;++nf) s += acc[nf][r]*acc[nf][r];
      s += __shfl_xor(s, 1); s += __shfl_xor(s, 2);
      s += __shfl_xor(s, 4); s += __shfl_xor(s, 8);
      rstd[r] = rsqrtf(s*(1.f/64.f) + 1e-6f);
    }
    const float extra = (qkv_t == 0) ? (SCALE_*LOG2E_) : 1.f;
#pragma unroll
    for (int nf=0;nf<4;++nf){
      int d = 16*nf + lr;
      float gv = g[d] * extra;
#pragma unroll
      for (int r=0;r<4;++r){
        int m = m0 + rowb + r;
        if (m < M_){
          int b = m / N_, n = m - b*N_;
          int bh = b*H_ + h;
          u16 val = f2bf(acc[nf][r]*rstd[r]*gv);
          if (qkv_t == 0)
            qn[((size_t)bh*QP_ + n)*64 + d] = val;
          else
            kn2[(size_t)bh*KVSZ_ + (n>>5)*2048 + ((d>>3)<<8) + ((n&31)<<3) + (d&7)] = val;
        }
      }
    }
  } else {
#pragma unroll
    for (int nf=0;nf<4;++nf)
#pragma unroll
      for (int r=0;r<4;++r)
        Cs[rowb + r][16*nf + lr] = f2bf(acc[nf][r]);
    __syncthreads();
    const int nl = tid & 63;
    const int db = tid >> 6;
    int m = m0 + nl;
    if (m < M_){
      int b = m / N_, n = m - b*N_;
      u16* vbase = v2 + (size_t)(b*H_ + h)*KVSZ_ + (n>>5)*2048 + (((n>>3)&3)<<9) + (n&7);
#pragma unroll
      for (int pass=0; pass<16; ++pass){
        int d = db + pass*4;
        vbase[d<<3] = Cs[nl][d];
      }
    }
  }
}

// ---------------- flash attention, fixed-max, 32x32 swapped-operand ----------------
// grid 2304 = 8 XCD-chunks x (32 b x 9 qt); 4 waves x 32 q-rows = 128-row q-block
__global__ __launch_bounds__(256, 4)
void k_attn2(const u16* __restrict__ qn, const u16* __restrict__ kn2, const u16* __restrict__ v2,
             const u16* __restrict__ br, u16* __restrict__ ao){
  __shared__ u16 Ks[2][2048];
  __shared__ u16 Vs[2][2048];
  const int tid = threadIdx.x;
  const int lane = tid & 63, wave = tid >> 6;
  const int il = lane & 31, hi = lane >> 5;
  int wg = ((blockIdx.x & 7) * 288) + (blockIdx.x >> 3);
  int h = wg / 288;
  int rem = wg - h*288;
  int b = rem / 9, qt = rem - (rem/9)*9;
  int bh = b*8 + h;
  int i0 = qt*128 + wave*32;

  // Q fragments (hoisted; q pre-scaled by SCALE*log2e in k_qkv)
  const u16* qp = qn + ((size_t)bh*QP_ + (i0 + il))*64 + hi*8;
  bf16x8 qf[4];
#pragma unroll
  for (int c=0;c<4;++c) qf[c] = *(const bf16x8*)(qp + 16*c);

  // staging: one fully-coalesced 4KB tile per gll16-pair; chunk-major layouts
  const u16* ksrc = kn2 + (size_t)bh*KVSZ_ + tid*8;
  const u16* vsrc = v2  + (size_t)bh*KVSZ_ + tid*8;

  gll16(ksrc, &Ks[0][wave*512]);
  gll16(vsrc, &Vs[0][wave*512]);

  f32x16 oA, oB, oS;
#pragma unroll
  for (int r=0;r<16;++r){ oA[r]=0.f; oB[r]=0.f; oS[r]=0.f; }

  const bf16x8 onesf = {0x3F80,0x3F80,0x3F80,0x3F80,0x3F80,0x3F80,0x3F80,0x3F80};

  const u16* bptr = br + (((size_t)(h*33))*BIP_ + (i0 + il))*32 + hi*16;
  bf16x8 bb0 = *(const bf16x8*)(bptr);
  bf16x8 bb1 = *(const bf16x8*)(bptr + 8);

  for (int t=0; t<33; ++t){
    const int cur = t & 1;
    __syncthreads();
    if (t < 32){
      gll16(ksrc + (t+1)*2048, &Ks[cur^1][wave*512]);
      gll16(vsrc + (t+1)*2048, &Vs[cur^1][wave*512]);
    }
    bf16x8 b0 = bb0, b1 = bb1;
    if (t < 32){
      bptr += (size_t)BIP_*32;
      bb0 = *(const bf16x8*)(bptr);
      bb1 = *(const bf16x8*)(bptr + 8);
    }

    // QK^T (swapped): S^T[j][i], lane holds q-row i=il, 16 j's
    f32x16 s;
#pragma unroll
    for (int r=0;r<16;++r) s[r] = 0.f;
    __builtin_amdgcn_s_setprio(1);
#pragma unroll
    for (int c=0;c<4;++c){
      bf16x8 kf = *(const bf16x8*)(&Ks[cur][0] + (2*c + hi)*256 + il*8);
      s = __builtin_amdgcn_mfma_f32_32x32x16_bf16(kf, qf[c], s, 0, 0, 0);
    }
    __builtin_amdgcn_s_setprio(0);

    // p = exp2(s + bias') : bias' pre-scaled by log2e, pre-offset by -12, pre-masked
#pragma unroll
    for (int r=0;r<16;++r){
      u16 bv = (r < 8) ? ((u16)b0[r]) : ((u16)b1[r-8]);
      float bf = __builtin_bit_cast(float, ((u32)bv) << 16);
      s[r] = __builtin_amdgcn_exp2f(s[r] + bf);
    }

    // pack P^T fragments: cvt_pk + permlane32_swap
    u32 X0 = cvtpk(s[0],s[1]),   X1 = cvtpk(s[2],s[3]);
    u32 Y0 = cvtpk(s[4],s[5]),   Y1 = cvtpk(s[6],s[7]);
    u32 X2 = cvtpk(s[8],s[9]),   X3 = cvtpk(s[10],s[11]);
    u32 Y2 = cvtpk(s[12],s[13]), Y3 = cvtpk(s[14],s[15]);
    pswap(X0, Y0); pswap(X1, Y1); pswap(X2, Y2); pswap(X3, Y3);
    u32x4 w0 = {X0, X1, Y0, Y1};
    u32x4 w1 = {X2, X3, Y2, Y3};
    bf16x8 pv0 = __builtin_bit_cast(bf16x8, w0);
    bf16x8 pv1 = __builtin_bit_cast(bf16x8, w1);

    // PV: O^T = V^T * P^T ; row-sums via ones-MFMA on the idle matrix pipe
    __builtin_amdgcn_s_setprio(1);
#pragma unroll
    for (int c2=0;c2<2;++c2){
      bf16x8 pv = c2 ? pv1 : pv0;
      const u16* vbase = &Vs[cur][0] + (2*c2 + hi)*512;
      bf16x8 vfA = *(const bf16x8*)(vbase + il*8);
      bf16x8 vfB = *(const bf16x8*)(vbase + 256 + il*8);
      oA = __builtin_amdgcn_mfma_f32_32x32x16_bf16(vfA, pv, oA, 0, 0, 0);
      oB = __builtin_amdgcn_mfma_f32_32x32x16_bf16(vfB, pv, oB, 0, 0, 0);
      oS = __builtin_amdgcn_mfma_f32_32x32x16_bf16(onesf, pv, oS, 0, 0, 0);
    }
    __builtin_amdgcn_s_setprio(0);
  }

  int i = i0 + il;
  if (i < N_){
    float inv = 1.f / oS[0];
    u16* op = ao + ((size_t)(b*N_ + i))*DIM_ + h*64;
#pragma unroll
    for (int q=0;q<4;++q)
#pragma unroll
      for (int pr=0;pr<2;++pr){
        int d0 = 8*q + 4*hi + 2*pr;
        u32 wA = cvtpk(oA[4*q+2*pr]*inv, oA[4*q+2*pr+1]*inv);
        u32 wB = cvtpk(oB[4*q+2*pr]*inv, oB[4*q+2*pr+1]*inv);
        *(u32*)(op + d0) = wA;
        *(u32*)(op + 32 + d0) = wB;
      }
  }
}

// ---------------- output projection ----------------
// grid (513, 8); tile 64 x 64
__global__ __launch_bounds__(256)
void k_oproj(const u16* __restrict__ ab, const u16* __restrict__ wT, const float* __restrict__ bo,
             float* __restrict__ out){
  __shared__ u16 As[2][2048];
  __shared__ u16 Bs[2][2048];
  const int tid = threadIdx.x;
  const int lane = tid & 63, wid = tid >> 6;
  const int lg = lane >> 4, lr = lane & 15;
  const int m0 = blockIdx.x * 64;
  const int n0 = blockIdx.y * 64;

  const int srow = tid >> 2;
  const int schunk = (tid & 3) ^ ((tid >> 3) & 3);
  const u16* asrc = ab + (size_t)(m0 + srow)*DIM_ + schunk*8;
  const u16* bsrc = wT + (size_t)(n0 + srow)*DIM_ + schunk*8;
  const int rsw = (lg ^ ((lr>>1)&3)) << 3;

  f32x4 acc[4];
#pragma unroll
  for (int i=0;i<4;++i) acc[i] = {0.f,0.f,0.f,0.f};

  gll16(asrc, &As[0][wid*512]);
  gll16(bsrc, &Bs[0][wid*512]);

  for (int s=0; s<16; ++s){
    const int cur = s & 1;
    __syncthreads();
    if (s < 15){
      gll16(asrc + (s+1)*32, &As[cur^1][wid*512]);
      gll16(bsrc + (s+1)*32, &Bs[cur^1][wid*512]);
    }
    bf16x8 af = *(const bf16x8*)&As[cur][(16*wid + lr)*32 + rsw];
#pragma unroll
    for (int nf=0; nf<4; ++nf){
      bf16x8 bfv = *(const bf16x8*)&Bs[cur][(16*nf + lr)*32 + rsw];
      acc[nf] = __builtin_amdgcn_mfma_f32_16x16x32_bf16(af, bfv, acc[nf], 0, 0, 0);
    }
  }
  const int rowb = 16*wid + 4*lg;
#pragma unroll
  for (int nf=0;nf<4;++nf){
    int nc = n0 + 16*nf + lr;
    float bb = bo[nc];
#pragma unroll
    for (int r=0;r<4;++r){
      int m = m0 + rowb + r;
      if (m < M_) out[(size_t)m*DIM_ + nc] = acc[nf][r] + bb;
    }
  }
}

// ---------------- launch ----------------
extern "C" void kernel_launch(void* const* d_in, const int* in_sizes, int n_in,
                              void* d_out, int out_size, void* d_ws, size_t ws_size,
                              hipStream_t stream) {
  const float* x     = (const float*)d_in[0];
  const float* w_qkv = (const float*)d_in[1];
  const float* g     = (const float*)d_in[2];
  const float* pe    = (const float*)d_in[3];
  const float* w_out = (const float*)d_in[4];
  const float* b_out = (const float*)d_in[5];
  const int*   bidx  = (const int*)d_in[6];
  float* out = (float*)d_out;

  char* ws = (char*)d_ws;
  u16* xb    = (u16*)(ws);                    // 33,587,200  (aliased: aob reuses after k_qkv)
  u16* wT    = (u16*)(ws + 33587200);         //  1,572,864
  u16* woT   = (u16*)(ws + 35160064);         //    524,288
  u16* qnb   = (u16*)(ws + 35684352);         // 37,748,736
  u16* kn2   = (u16*)(ws + 73433088);         // 34,603,008
  u16* v2    = (u16*)(ws + 108036096);        // 34,603,008
  u16* biasr = (u16*)(ws + 142639104);        // 19,464,192  (end 162,103,296)
  u16* aob   = xb;                            // alias: xb dead after k_qkv

  int n4 = (B_*N_*DIM_)/4;
  k_conv_x<<<(n4+255)/256, 256, 0, stream>>>(x, xb, n4);
  k_transpose<<<(1536*512+255)/256, 256, 0, stream>>>(w_qkv, wT, 512, 1536);
  k_transpose<<<(512*512+255)/256, 256, 0, stream>>>(w_out, woT, 512, 512);
  k_biasr<<<38016, 256, 0, stream>>>(bidx, pe, biasr);
  k_ztail<<<12096, 256, 0, stream>>>(qnb, kn2, v2);

  dim3 gq(513, 24);
  k_qkv<<<gq, 256, 0, stream>>>(xb, wT, g, qnb, kn2, v2);
  k_attn2<<<2304, 256, 0, stream>>>(qnb, kn2, v2, biasr, aob);
  dim3 go(513, 8);
  k_oproj<<<go, 256, 0, stream>>>(aob, woT, b_out, out);
}

// Round 4
// 300.314 us; speedup vs baseline: 2.3759x; 1.2865x over previous
//
#include <hip/hip_runtime.h>

typedef short bf16x8 __attribute__((ext_vector_type(8)));
typedef float f32x4 __attribute__((ext_vector_type(4)));
typedef float f32x16 __attribute__((ext_vector_type(16)));
typedef unsigned int u32;
typedef u32 u32x4 __attribute__((ext_vector_type(4)));
typedef unsigned short u16;

#define B_    32
#define N_    1025
#define H_    8
#define DIM_  512
#define M_    (B_*N_)      // 32800
#define QP_   1152         // qn row pitch per bh
#define BIP_  1152         // bias_r i pitch
#define KVSZ_ 67584        // per-bh u16 size of kn2/v2 (33 tiles * 2048)
#define SCALE_ 0.125f
#define LOG2E_ 1.4426950408889634f
#define COFF_  12.0f       // fixed softmax offset (max |s*log2e| < 11.8)

__device__ __forceinline__ u16 f2bf(float f){
  unsigned u = __builtin_bit_cast(unsigned, f);
  u += 0x7FFFu + ((u >> 16) & 1u);
  return (u16)(u >> 16);
}
__device__ __forceinline__ u32 cvtpk(float a, float b){
  u32 r;
  asm("v_cvt_pk_bf16_f32 %0, %1, %2" : "=v"(r) : "v"(a), "v"(b));
  return r;
}
__device__ __forceinline__ void pswap(u32 &a, u32 &b){
  asm("v_permlane32_swap_b32 %0, %1" : "+v"(a), "+v"(b));
}
__device__ __forceinline__ void gll16(const u16* g, u16* l){
  __builtin_amdgcn_global_load_lds((const __attribute__((address_space(1))) u16*)(g),
                                   (__attribute__((address_space(3))) u16*)(l), 16, 0, 0);
}

// ---------------- prep kernels ----------------
__global__ __launch_bounds__(256)
void k_conv_x(const float* __restrict__ x, u16* __restrict__ o, int n4){
  int i = blockIdx.x*256 + threadIdx.x;
  if (i >= n4) return;
  float4 v = ((const float4*)x)[i];
  ushort4 r;
  r.x = f2bf(v.x); r.y = f2bf(v.y); r.z = f2bf(v.z); r.w = f2bf(v.w);
  ((ushort4*)o)[i] = r;
}

__global__ __launch_bounds__(256)
void k_transpose(const float* __restrict__ w, u16* __restrict__ wt, int R, int C){
  int i = blockIdx.x*256 + threadIdx.x;
  if (i >= R*C) return;
  int n = i / R, k = i - n*R;
  wt[i] = f2bf(w[k*C + n]);
}

// bias_r[h][jt(33)][i(1152)][hi(2)][16 regs]; value = pe*log2e - COFF (masked)
__global__ __launch_bounds__(256)
void k_biasr(const int* __restrict__ idx, const float* __restrict__ pe, u16* __restrict__ br){
  int i_lin = blockIdx.x*256 + threadIdx.x;  // 8*33*1152*32 total
  int v = i_lin & 15, hi = (i_lin>>4)&1;
  int t1 = i_lin >> 5;
  int i = t1 % 1152;
  int t2 = t1 / 1152;
  int tj = t2 % 33;
  int h = t2 / 33;
  int j = tj*32 + (v&3) + 8*(v>>2) + 4*hi;
  float val;
  if (j >= 1 && j <= 1024 && i >= 1 && i <= 1024)
    val = pe[idx[(i-1)*1024 + (j-1)]*8 + h] * LOG2E_ - COFF_;
  else
    val = (j <= 1024) ? -COFF_ : -1e9f;
  br[i_lin] = f2bf(val);
}

// zero tails: qn rows [1025,1152); kn2 tile-32 j in [1,32); v2 tile-32 j in [1,32)
__global__ __launch_bounds__(256)
void k_ztail(u16* __restrict__ qn, u16* __restrict__ kn2, u16* __restrict__ v2){
  int i = blockIdx.x*256 + threadIdx.x;
  if (i < 2080768){
    int bh = i / (127*64); int r = i - bh*(127*64);
    qn[((size_t)bh*QP_ + 1025 + (r>>6))*64 + (r&63)] = 0;
  } else if (i < 2588672){
    int k = i - 2080768; int bh = k/1984; int r = k - bh*1984;
    int n = 1025 + (r>>6), d = r & 63;
    kn2[(size_t)bh*KVSZ_ + 65536 + ((d>>3)<<8) + ((n&31)<<3) + (d&7)] = 0;
  } else if (i < 3096576){
    int k = i - 2588672; int bh = k/1984; int r = k - bh*1984;
    int n = 1025 + (r>>6), d = r & 63;
    v2[(size_t)bh*KVSZ_ + 65536 + (((n>>3)&3)<<9) + (d<<3) + (n&7)] = 0;
  }
}

// ---------------- QKV GEMM (128x128 tile) + fused RMSNorm / rearrange ----------------
// grid 3084 = 257 M-tiles x 12 N-tiles; 4 waves 2x2, each 64x64 quadrant
__global__ __launch_bounds__(256)
void k_qkv(const u16* __restrict__ xb, const u16* __restrict__ wT, const float* __restrict__ g,
           u16* __restrict__ qn, u16* __restrict__ kn2, u16* __restrict__ v2){
  __shared__ u16 sh[16384];   // As[2][4096] | Bs[2][4096]
  const int tid = threadIdx.x;
  const int lane = tid & 63, wid = tid >> 6;
  const int lg = lane >> 4, lr = lane & 15;
  const int wm = wid >> 1, wn = wid & 1;

  // bijective XCD swizzle (nwg=3084, q=385, r=4); within XCD: nt fastest
  int orig = blockIdx.x;
  int xcd = orig & 7, idx = orig >> 3;
  int wgid = (xcd < 4 ? xcd*386 : 1544 + (xcd-4)*385) + idx;
  int mt = wgid / 12, nt = wgid - mt*12;
  const int m0 = mt*128, n0 = nt*128;
  const int qkv_t = nt >> 2;
  const int h = ((nt & 3) << 1) + wn;

  const int srow = tid >> 2;
  const int schunk = (tid & 3) ^ ((tid >> 3) & 3);
  const u16* asrc = xb + (size_t)(m0 + srow)*DIM_ + schunk*8;
  const u16* bsrc = wT + (size_t)(n0 + srow)*DIM_ + schunk*8;
  const int rsw = (lg ^ ((lr>>1)&3)) << 3;

  u16* As = sh;
  u16* Bs = sh + 8192;

  f32x4 acc[4][4];
#pragma unroll
  for (int m=0;m<4;++m)
#pragma unroll
    for (int n=0;n<4;++n) acc[m][n] = {0.f,0.f,0.f,0.f};

  gll16(asrc,            As + wid*512);
  gll16(asrc + 64*DIM_,  As + 2048 + wid*512);
  gll16(bsrc,            Bs + wid*512);
  gll16(bsrc + 64*DIM_,  Bs + 2048 + wid*512);

  for (int s=0; s<16; ++s){
    const int cur = s & 1;
    __syncthreads();
    if (s < 15){
      const int ko = (s+1)*32;
      gll16(asrc + ko,           As + (cur^1)*4096 + wid*512);
      gll16(asrc + ko + 64*DIM_, As + (cur^1)*4096 + 2048 + wid*512);
      gll16(bsrc + ko,           Bs + (cur^1)*4096 + wid*512);
      gll16(bsrc + ko + 64*DIM_, Bs + (cur^1)*4096 + 2048 + wid*512);
    }
    bf16x8 af[4], bf[4];
#pragma unroll
    for (int m=0;m<4;++m) af[m] = *(const bf16x8*)(As + cur*4096 + (64*wm+16*m+lr)*32 + rsw);
#pragma unroll
    for (int n=0;n<4;++n) bf[n] = *(const bf16x8*)(Bs + cur*4096 + (64*wn+16*n+lr)*32 + rsw);
    __builtin_amdgcn_s_setprio(1);
#pragma unroll
    for (int m=0;m<4;++m)
#pragma unroll
      for (int n=0;n<4;++n)
        acc[m][n] = __builtin_amdgcn_mfma_f32_16x16x32_bf16(af[m], bf[n], acc[m][n], 0, 0, 0);
    __builtin_amdgcn_s_setprio(0);
  }

  // unified epilogue: rows 64*wm+16m+4lg+r, head h, d = 16n+lr
  float gv[4];
#pragma unroll
  for (int n=0;n<4;++n)
    gv[n] = (qkv_t==0) ? g[16*n+lr]*(SCALE_*LOG2E_) : (qkv_t==1 ? g[16*n+lr] : 1.f);

#pragma unroll
  for (int m=0;m<4;++m){
    float rstd[4];
    if (qkv_t < 2){
#pragma unroll
      for (int r=0;r<4;++r){
        float s = 0.f;
#pragma unroll
        for (int n=0;n<4;++n) s += acc[m][n][r]*acc[m][n][r];
        s += __shfl_xor(s, 1); s += __shfl_xor(s, 2);
        s += __shfl_xor(s, 4); s += __shfl_xor(s, 8);
        rstd[r] = rsqrtf(s*(1.f/64.f) + 1e-6f);
      }
    } else {
#pragma unroll
      for (int r=0;r<4;++r) rstd[r] = 1.f;
    }
#pragma unroll
    for (int r=0;r<4;++r){
      int mg = m0 + 64*wm + 16*m + 4*lg + r;
      if (mg < M_){
        int b = mg / N_, pos = mg - b*N_;
        int bh = b*H_ + h;
#pragma unroll
        for (int n=0;n<4;++n){
          int d = 16*n + lr;
          u16 val = f2bf(acc[m][n][r]*rstd[r]*gv[n]);
          if (qkv_t == 0)
            qn[((size_t)bh*QP_ + pos)*64 + d] = val;
          else if (qkv_t == 1)
            kn2[(size_t)bh*KVSZ_ + (pos>>5)*2048 + ((d>>3)<<8) + ((pos&31)<<3) + (d&7)] = val;
          else
            v2[(size_t)bh*KVSZ_ + (pos>>5)*2048 + (((pos>>3)&3)<<9) + (d<<3) + (pos&7)] = val;
        }
      }
    }
  }
}

// ---------------- flash attention, fixed-max, 32x32 swapped-operand ----------------
// grid 2304 = 8 XCD-chunks x (32 b x 9 qt); 4 waves x 32 q-rows = 128-row q-block
__global__ __launch_bounds__(256, 4)
void k_attn2(const u16* __restrict__ qn, const u16* __restrict__ kn2, const u16* __restrict__ v2,
             const u16* __restrict__ br, u16* __restrict__ ao){
  __shared__ u16 Ks[2][2048];
  __shared__ u16 Vs[2][2048];
  const int tid = threadIdx.x;
  const int lane = tid & 63, wave = tid >> 6;
  const int il = lane & 31, hi = lane >> 5;
  int wg = ((blockIdx.x & 7) * 288) + (blockIdx.x >> 3);
  int h = wg / 288;
  int rem = wg - h*288;
  int b = rem / 9, qt = rem - (rem/9)*9;
  int bh = b*8 + h;
  int i0 = qt*128 + wave*32;

  // Q fragments (hoisted; q pre-scaled by SCALE*log2e in k_qkv)
  const u16* qp = qn + ((size_t)bh*QP_ + (i0 + il))*64 + hi*8;
  bf16x8 qf[4];
#pragma unroll
  for (int c=0;c<4;++c) qf[c] = *(const bf16x8*)(qp + 16*c);

  // staging: one fully-coalesced 4KB tile per gll16-pair; chunk-major layouts
  const u16* ksrc = kn2 + (size_t)bh*KVSZ_ + tid*8;
  const u16* vsrc = v2  + (size_t)bh*KVSZ_ + tid*8;

  gll16(ksrc, &Ks[0][wave*512]);
  gll16(vsrc, &Vs[0][wave*512]);

  f32x16 oA, oB, oS;
#pragma unroll
  for (int r=0;r<16;++r){ oA[r]=0.f; oB[r]=0.f; oS[r]=0.f; }

  const bf16x8 onesf = {0x3F80,0x3F80,0x3F80,0x3F80,0x3F80,0x3F80,0x3F80,0x3F80};

  const u16* bptr = br + (((size_t)(h*33))*BIP_ + (i0 + il))*32 + hi*16;
  bf16x8 bb0 = *(const bf16x8*)(bptr);
  bf16x8 bb1 = *(const bf16x8*)(bptr + 8);

  for (int t=0; t<33; ++t){
    const int cur = t & 1;
    __syncthreads();
    if (t < 32){
      gll16(ksrc + (t+1)*2048, &Ks[cur^1][wave*512]);
      gll16(vsrc + (t+1)*2048, &Vs[cur^1][wave*512]);
    }
    bf16x8 b0 = bb0, b1 = bb1;
    if (t < 32){
      bptr += (size_t)BIP_*32;
      bb0 = *(const bf16x8*)(bptr);
      bb1 = *(const bf16x8*)(bptr + 8);
    }

    // QK^T (swapped): S^T[j][i], lane holds q-row i=il, 16 j's
    f32x16 s;
#pragma unroll
    for (int r=0;r<16;++r) s[r] = 0.f;
    __builtin_amdgcn_s_setprio(1);
#pragma unroll
    for (int c=0;c<4;++c){
      bf16x8 kf = *(const bf16x8*)(&Ks[cur][0] + (2*c + hi)*256 + il*8);
      s = __builtin_amdgcn_mfma_f32_32x32x16_bf16(kf, qf[c], s, 0, 0, 0);
    }
    __builtin_amdgcn_s_setprio(0);

    // p = exp2(s + bias') : bias' pre-scaled by log2e, pre-offset by -12, pre-masked
#pragma unroll
    for (int r=0;r<16;++r){
      u16 bv = (r < 8) ? ((u16)b0[r]) : ((u16)b1[r-8]);
      float bf = __builtin_bit_cast(float, ((u32)bv) << 16);
      s[r] = __builtin_amdgcn_exp2f(s[r] + bf);
    }

    // pack P^T fragments: cvt_pk + permlane32_swap
    u32 X0 = cvtpk(s[0],s[1]),   X1 = cvtpk(s[2],s[3]);
    u32 Y0 = cvtpk(s[4],s[5]),   Y1 = cvtpk(s[6],s[7]);
    u32 X2 = cvtpk(s[8],s[9]),   X3 = cvtpk(s[10],s[11]);
    u32 Y2 = cvtpk(s[12],s[13]), Y3 = cvtpk(s[14],s[15]);
    pswap(X0, Y0); pswap(X1, Y1); pswap(X2, Y2); pswap(X3, Y3);
    u32x4 w0 = {X0, X1, Y0, Y1};
    u32x4 w1 = {X2, X3, Y2, Y3};
    bf16x8 pv0 = __builtin_bit_cast(bf16x8, w0);
    bf16x8 pv1 = __builtin_bit_cast(bf16x8, w1);

    // PV: O^T = V^T * P^T ; row-sums via ones-MFMA on the idle matrix pipe
    __builtin_amdgcn_s_setprio(1);
#pragma unroll
    for (int c2=0;c2<2;++c2){
      bf16x8 pv = c2 ? pv1 : pv0;
      const u16* vbase = &Vs[cur][0] + (2*c2 + hi)*512;
      bf16x8 vfA = *(const bf16x8*)(vbase + il*8);
      bf16x8 vfB = *(const bf16x8*)(vbase + 256 + il*8);
      oA = __builtin_amdgcn_mfma_f32_32x32x16_bf16(vfA, pv, oA, 0, 0, 0);
      oB = __builtin_amdgcn_mfma_f32_32x32x16_bf16(vfB, pv, oB, 0, 0, 0);
      oS = __builtin_amdgcn_mfma_f32_32x32x16_bf16(onesf, pv, oS, 0, 0, 0);
    }
    __builtin_amdgcn_s_setprio(0);
  }

  int i = i0 + il;
  if (i < N_){
    float inv = 1.f / oS[0];
    u16* op = ao + ((size_t)(b*N_ + i))*DIM_ + h*64;
#pragma unroll
    for (int q=0;q<4;++q)
#pragma unroll
      for (int pr=0;pr<2;++pr){
        int d0 = 8*q + 4*hi + 2*pr;
        u32 wA = cvtpk(oA[4*q+2*pr]*inv, oA[4*q+2*pr+1]*inv);
        u32 wB = cvtpk(oB[4*q+2*pr]*inv, oB[4*q+2*pr+1]*inv);
        *(u32*)(op + d0) = wA;
        *(u32*)(op + 32 + d0) = wB;
      }
  }
}

// ---------------- output projection (128x128 tile) ----------------
// grid 1028 = 257 x 4
__global__ __launch_bounds__(256)
void k_oproj(const u16* __restrict__ ab, const u16* __restrict__ wT, const float* __restrict__ bo,
             float* __restrict__ out){
  __shared__ u16 sh[16384];
  const int tid = threadIdx.x;
  const int lane = tid & 63, wid = tid >> 6;
  const int lg = lane >> 4, lr = lane & 15;
  const int wm = wid >> 1, wn = wid & 1;

  // bijective XCD swizzle (nwg=1028, q=128, r=4)
  int orig = blockIdx.x;
  int xcd = orig & 7, idx = orig >> 3;
  int wgid = (xcd < 4 ? xcd*129 : 516 + (xcd-4)*128) + idx;
  int mt = wgid >> 2, nt = wgid & 3;
  const int m0 = mt*128, n0 = nt*128;

  const int srow = tid >> 2;
  const int schunk = (tid & 3) ^ ((tid >> 3) & 3);
  const u16* asrc = ab + (size_t)(m0 + srow)*DIM_ + schunk*8;
  const u16* bsrc = wT + (size_t)(n0 + srow)*DIM_ + schunk*8;
  const int rsw = (lg ^ ((lr>>1)&3)) << 3;

  u16* As = sh;
  u16* Bs = sh + 8192;

  f32x4 acc[4][4];
#pragma unroll
  for (int m=0;m<4;++m)
#pragma unroll
    for (int n=0;n<4;++n) acc[m][n] = {0.f,0.f,0.f,0.f};

  gll16(asrc,            As + wid*512);
  gll16(asrc + 64*DIM_,  As + 2048 + wid*512);
  gll16(bsrc,            Bs + wid*512);
  gll16(bsrc + 64*DIM_,  Bs + 2048 + wid*512);

  for (int s=0; s<16; ++s){
    const int cur = s & 1;
    __syncthreads();
    if (s < 15){
      const int ko = (s+1)*32;
      gll16(asrc + ko,           As + (cur^1)*4096 + wid*512);
      gll16(asrc + ko + 64*DIM_, As + (cur^1)*4096 + 2048 + wid*512);
      gll16(bsrc + ko,           Bs + (cur^1)*4096 + wid*512);
      gll16(bsrc + ko + 64*DIM_, Bs + (cur^1)*4096 + 2048 + wid*512);
    }
    bf16x8 af[4], bf[4];
#pragma unroll
    for (int m=0;m<4;++m) af[m] = *(const bf16x8*)(As + cur*4096 + (64*wm+16*m+lr)*32 + rsw);
#pragma unroll
    for (int n=0;n<4;++n) bf[n] = *(const bf16x8*)(Bs + cur*4096 + (64*wn+16*n+lr)*32 + rsw);
    __builtin_amdgcn_s_setprio(1);
#pragma unroll
    for (int m=0;m<4;++m)
#pragma unroll
      for (int n=0;n<4;++n)
        acc[m][n] = __builtin_amdgcn_mfma_f32_16x16x32_bf16(af[m], bf[n], acc[m][n], 0, 0, 0);
    __builtin_amdgcn_s_setprio(0);
  }

  float bb[4];
#pragma unroll
  for (int n=0;n<4;++n) bb[n] = bo[n0 + 64*wn + 16*n + lr];
#pragma unroll
  for (int m=0;m<4;++m)
#pragma unroll
    for (int r=0;r<4;++r){
      int mg = m0 + 64*wm + 16*m + 4*lg + r;
      if (mg < M_){
#pragma unroll
        for (int n=0;n<4;++n)
          out[(size_t)mg*DIM_ + n0 + 64*wn + 16*n + lr] = acc[m][n][r] + bb[n];
      }
    }
}

// ---------------- launch ----------------
extern "C" void kernel_launch(void* const* d_in, const int* in_sizes, int n_in,
                              void* d_out, int out_size, void* d_ws, size_t ws_size,
                              hipStream_t stream) {
  const float* x     = (const float*)d_in[0];
  const float* w_qkv = (const float*)d_in[1];
  const float* g     = (const float*)d_in[2];
  const float* pe    = (const float*)d_in[3];
  const float* w_out = (const float*)d_in[4];
  const float* b_out = (const float*)d_in[5];
  const int*   bidx  = (const int*)d_in[6];
  float* out = (float*)d_out;

  char* ws = (char*)d_ws;
  u16* xb    = (u16*)(ws);                    // 33,587,200  (aliased: aob reuses after k_qkv)
  u16* wT    = (u16*)(ws + 33587200);         //  1,572,864
  u16* woT   = (u16*)(ws + 35160064);         //    524,288
  u16* qnb   = (u16*)(ws + 35684352);         // 37,748,736
  u16* kn2   = (u16*)(ws + 73433088);         // 34,603,008
  u16* v2    = (u16*)(ws + 108036096);        // 34,603,008
  u16* biasr = (u16*)(ws + 142639104);        // 19,464,192  (end 162,103,296)
  u16* aob   = xb;                            // alias: xb dead after k_qkv

  int n4 = (B_*N_*DIM_)/4;
  k_conv_x<<<(n4+255)/256, 256, 0, stream>>>(x, xb, n4);
  k_transpose<<<(1536*512+255)/256, 256, 0, stream>>>(w_qkv, wT, 512, 1536);
  k_transpose<<<(512*512+255)/256, 256, 0, stream>>>(w_out, woT, 512, 512);
  k_biasr<<<38016, 256, 0, stream>>>(bidx, pe, biasr);
  k_ztail<<<12096, 256, 0, stream>>>(qnb, kn2, v2);

  k_qkv<<<3084, 256, 0, stream>>>(xb, wT, g, qnb, kn2, v2);
  k_attn2<<<2304, 256, 0, stream>>>(qnb, kn2, v2, biasr, aob);
  k_oproj<<<1028, 256, 0, stream>>>(aob, woT, b_out, out);
}

// Round 5
// 295.701 us; speedup vs baseline: 2.4129x; 1.0156x over previous
//
#include <hip/hip_runtime.h>

typedef short bf16x8 __attribute__((ext_vector_type(8)));
typedef float f32x4 __attribute__((ext_vector_type(4)));
typedef float f32x16 __attribute__((ext_vector_type(16)));
typedef unsigned int u32;
typedef u32 u32x4 __attribute__((ext_vector_type(4)));
typedef unsigned short u16;

#define B_    32
#define N_    1025
#define H_    8
#define DIM_  512
#define M_    (B_*N_)      // 32800
#define QP_   1152         // qn row pitch per bh
#define BIP_  1152         // bias_r i pitch
#define NT_   34           // KV/bias tiles incl. 1 pad tile (prefetch guard-free)
#define KVSZ_ (NT_*2048)   // per-bh u16 size of kn2/v2
#define BT_   (BIP_*32)    // bias tile stride (u16)
#define SCALE_ 0.125f
#define LOG2E_ 1.4426950408889634f

__device__ __forceinline__ u16 f2bf(float f){
  unsigned u = __builtin_bit_cast(unsigned, f);
  u += 0x7FFFu + ((u >> 16) & 1u);
  return (u16)(u >> 16);
}
__device__ __forceinline__ u32 cvtpk(float a, float b){
  u32 r;
  asm("v_cvt_pk_bf16_f32 %0, %1, %2" : "=v"(r) : "v"(a), "v"(b));
  return r;
}
__device__ __forceinline__ void pswap(u32 &a, u32 &b){
  asm("v_permlane32_swap_b32 %0, %1" : "+v"(a), "+v"(b));
}
__device__ __forceinline__ void gll16(const u16* g, u16* l){
  __builtin_amdgcn_global_load_lds((const __attribute__((address_space(1))) u16*)(g),
                                   (__attribute__((address_space(3))) u16*)(l), 16, 0, 0);
}

// ---------------- prep kernels ----------------
__global__ __launch_bounds__(256)
void k_conv_x(const float* __restrict__ x, u16* __restrict__ o, int n4){
  int i = blockIdx.x*256 + threadIdx.x;
  if (i >= n4) return;
  float4 v = ((const float4*)x)[i];
  ushort4 r;
  r.x = f2bf(v.x); r.y = f2bf(v.y); r.z = f2bf(v.z); r.w = f2bf(v.w);
  ((ushort4*)o)[i] = r;
}

__global__ __launch_bounds__(256)
void k_transpose(const float* __restrict__ w, u16* __restrict__ wt, int R, int C){
  int i = blockIdx.x*256 + threadIdx.x;
  if (i >= R*C) return;
  int n = i / R, k = i - n*R;
  wt[i] = f2bf(w[k*C + n]);
}

// bias_r[h][tj(34)][i(1152)][hi(2)][16 regs]; value = pe*log2e (masked; no offset)
__global__ __launch_bounds__(256)
void k_biasr(const int* __restrict__ idx, const float* __restrict__ pe, u16* __restrict__ br){
  int i_lin = blockIdx.x*256 + threadIdx.x;  // 8*34*1152*32 total
  int v = i_lin & 15, hi = (i_lin>>4)&1;
  int t1 = i_lin >> 5;
  int i = t1 % 1152;
  int t2 = t1 / 1152;
  int tj = t2 % NT_;
  int h = t2 / NT_;
  int j = tj*32 + (v&3) + 8*(v>>2) + 4*hi;
  float val;
  if (j >= 1 && j <= 1024 && i >= 1 && i <= 1024)
    val = pe[idx[(i-1)*1024 + (j-1)]*8 + h] * LOG2E_;
  else
    val = (j <= 1024) ? 0.f : -1e9f;
  br[i_lin] = f2bf(val);
}

// zero tails: qn rows [1025,1152); kn2 tile-32 j in [1025,1056); v2 same
__global__ __launch_bounds__(256)
void k_ztail(u16* __restrict__ qn, u16* __restrict__ kn2, u16* __restrict__ v2){
  int i = blockIdx.x*256 + threadIdx.x;
  if (i < 2080768){
    int bh = i / (127*64); int r = i - bh*(127*64);
    qn[((size_t)bh*QP_ + 1025 + (r>>6))*64 + (r&63)] = 0;
  } else if (i < 2588672){
    int k = i - 2080768; int bh = k/1984; int r = k - bh*1984;
    int n = 1025 + (r>>6), d = r & 63;
    kn2[(size_t)bh*KVSZ_ + 65536 + ((d>>3)<<8) + ((n&31)<<3) + (d&7)] = 0;
  } else if (i < 3096576){
    int k = i - 2588672; int bh = k/1984; int r = k - bh*1984;
    int n = 1025 + (r>>6), d = r & 63;
    v2[(size_t)bh*KVSZ_ + 65536 + (((n>>3)&3)<<9) + (d<<3) + (n&7)] = 0;
  }
}

// ---------------- QKV GEMM (128x128 tile) + fused RMSNorm / rearrange ----------------
// grid 3084 = 257 M-tiles x 12 N-tiles; 4 waves 2x2, each 64x64 quadrant
__global__ __launch_bounds__(256)
void k_qkv(const u16* __restrict__ xb, const u16* __restrict__ wT, const float* __restrict__ g,
           u16* __restrict__ qn, u16* __restrict__ kn2, u16* __restrict__ v2){
  __shared__ u16 sh[16384];   // As[2][4096] | Bs[2][4096]
  const int tid = threadIdx.x;
  const int lane = tid & 63, wid = tid >> 6;
  const int lg = lane >> 4, lr = lane & 15;
  const int wm = wid >> 1, wn = wid & 1;

  // bijective XCD swizzle (nwg=3084, q=385, r=4); within XCD: nt fastest
  int orig = blockIdx.x;
  int xcd = orig & 7, idx = orig >> 3;
  int wgid = (xcd < 4 ? xcd*386 : 1544 + (xcd-4)*385) + idx;
  int mt = wgid / 12, nt = wgid - mt*12;
  const int m0 = mt*128, n0 = nt*128;
  const int qkv_t = nt >> 2;
  const int h = ((nt & 3) << 1) + wn;

  const int srow = tid >> 2;
  const int schunk = (tid & 3) ^ ((tid >> 3) & 3);
  const u16* asrc = xb + (size_t)(m0 + srow)*DIM_ + schunk*8;
  const u16* bsrc = wT + (size_t)(n0 + srow)*DIM_ + schunk*8;
  const int rsw = (lg ^ ((lr>>1)&3)) << 3;

  u16* As = sh;
  u16* Bs = sh + 8192;

  f32x4 acc[4][4];
#pragma unroll
  for (int m=0;m<4;++m)
#pragma unroll
    for (int n=0;n<4;++n) acc[m][n] = {0.f,0.f,0.f,0.f};

  gll16(asrc,            As + wid*512);
  gll16(asrc + 64*DIM_,  As + 2048 + wid*512);
  gll16(bsrc,            Bs + wid*512);
  gll16(bsrc + 64*DIM_,  Bs + 2048 + wid*512);

  for (int s=0; s<16; ++s){
    const int cur = s & 1;
    __syncthreads();
    if (s < 15){
      const int ko = (s+1)*32;
      gll16(asrc + ko,           As + (cur^1)*4096 + wid*512);
      gll16(asrc + ko + 64*DIM_, As + (cur^1)*4096 + 2048 + wid*512);
      gll16(bsrc + ko,           Bs + (cur^1)*4096 + wid*512);
      gll16(bsrc + ko + 64*DIM_, Bs + (cur^1)*4096 + 2048 + wid*512);
    }
    bf16x8 af[4], bf[4];
#pragma unroll
    for (int m=0;m<4;++m) af[m] = *(const bf16x8*)(As + cur*4096 + (64*wm+16*m+lr)*32 + rsw);
#pragma unroll
    for (int n=0;n<4;++n) bf[n] = *(const bf16x8*)(Bs + cur*4096 + (64*wn+16*n+lr)*32 + rsw);
    __builtin_amdgcn_s_setprio(1);
#pragma unroll
    for (int m=0;m<4;++m)
#pragma unroll
      for (int n=0;n<4;++n)
        acc[m][n] = __builtin_amdgcn_mfma_f32_16x16x32_bf16(af[m], bf[n], acc[m][n], 0, 0, 0);
    __builtin_amdgcn_s_setprio(0);
  }

  // unified epilogue: rows 64*wm+16m+4lg+r, head h, d = 16n+lr
  float gv[4];
#pragma unroll
  for (int n=0;n<4;++n)
    gv[n] = (qkv_t==0) ? g[16*n+lr]*(SCALE_*LOG2E_) : (qkv_t==1 ? g[16*n+lr] : 1.f);

#pragma unroll
  for (int m=0;m<4;++m){
    float rstd[4];
    if (qkv_t < 2){
#pragma unroll
      for (int r=0;r<4;++r){
        float s = 0.f;
#pragma unroll
        for (int n=0;n<4;++n) s += acc[m][n][r]*acc[m][n][r];
        s += __shfl_xor(s, 1); s += __shfl_xor(s, 2);
        s += __shfl_xor(s, 4); s += __shfl_xor(s, 8);
        rstd[r] = rsqrtf(s*(1.f/64.f) + 1e-6f);
      }
    } else {
#pragma unroll
      for (int r=0;r<4;++r) rstd[r] = 1.f;
    }
#pragma unroll
    for (int r=0;r<4;++r){
      int mg = m0 + 64*wm + 16*m + 4*lg + r;
      if (mg < M_){
        int b = mg / N_, pos = mg - b*N_;
        int bh = b*H_ + h;
#pragma unroll
        for (int n=0;n<4;++n){
          int d = 16*n + lr;
          u16 val = f2bf(acc[m][n][r]*rstd[r]*gv[n]);
          if (qkv_t == 0)
            qn[((size_t)bh*QP_ + pos)*64 + d] = val;
          else if (qkv_t == 1)
            kn2[(size_t)bh*KVSZ_ + (pos>>5)*2048 + ((d>>3)<<8) + ((pos&31)<<3) + (d&7)] = val;
          else
            v2[(size_t)bh*KVSZ_ + (pos>>5)*2048 + (((pos>>3)&3)<<9) + (d<<3) + (pos&7)] = val;
        }
      }
    }
  }
}

// ---------------- flash attention: fixed-max, bias-as-C-init, 2-tile pairs ----------------
// grid 2304 = 8 XCD-chunks x (32 b x 9 qt); 4 waves x 32 q-rows = 128-row q-block
#define TILE(buf, off, B0, B1) do { \
  f32x16 s; \
  _Pragma("unroll") \
  for (int r=0;r<16;++r){ \
    u16 bv = (r < 8) ? ((u16)(B0)[r]) : ((u16)(B1)[r-8]); \
    s[r] = __builtin_bit_cast(float, ((u32)bv) << 16); \
  } \
  __builtin_amdgcn_s_setprio(1); \
  _Pragma("unroll") \
  for (int c=0;c<4;++c){ \
    bf16x8 kf = *(const bf16x8*)(&Ks[buf][0] + (off) + (2*c + hi)*256 + il*8); \
    s = __builtin_amdgcn_mfma_f32_32x32x16_bf16(kf, qf[c], s, 0, 0, 0); \
  } \
  __builtin_amdgcn_s_setprio(0); \
  _Pragma("unroll") \
  for (int r=0;r<16;++r) s[r] = __builtin_amdgcn_exp2f(s[r]); \
  u32 X0 = cvtpk(s[0],s[1]),   X1 = cvtpk(s[2],s[3]); \
  u32 Y0 = cvtpk(s[4],s[5]),   Y1 = cvtpk(s[6],s[7]); \
  u32 X2 = cvtpk(s[8],s[9]),   X3 = cvtpk(s[10],s[11]); \
  u32 Y2 = cvtpk(s[12],s[13]), Y3 = cvtpk(s[14],s[15]); \
  pswap(X0, Y0); pswap(X1, Y1); pswap(X2, Y2); pswap(X3, Y3); \
  u32x4 w0 = {X0, X1, Y0, Y1}; \
  u32x4 w1 = {X2, X3, Y2, Y3}; \
  bf16x8 pv0 = __builtin_bit_cast(bf16x8, w0); \
  bf16x8 pv1 = __builtin_bit_cast(bf16x8, w1); \
  __builtin_amdgcn_s_setprio(1); \
  _Pragma("unroll") \
  for (int c2=0;c2<2;++c2){ \
    bf16x8 pv = c2 ? pv1 : pv0; \
    const u16* vb = &Vs[buf][0] + (off) + (2*c2 + hi)*512; \
    bf16x8 vfA = *(const bf16x8*)(vb + il*8); \
    bf16x8 vfB = *(const bf16x8*)(vb + 256 + il*8); \
    oA = __builtin_amdgcn_mfma_f32_32x32x16_bf16(vfA, pv, oA, 0, 0, 0); \
    oB = __builtin_amdgcn_mfma_f32_32x32x16_bf16(vfB, pv, oB, 0, 0, 0); \
    oS = __builtin_amdgcn_mfma_f32_32x32x16_bf16(onesf, pv, oS, 0, 0, 0); \
  } \
  __builtin_amdgcn_s_setprio(0); \
} while(0)

__global__ __launch_bounds__(256, 3)
void k_attn2(const u16* __restrict__ qn, const u16* __restrict__ kn2, const u16* __restrict__ v2,
             const u16* __restrict__ br, u16* __restrict__ ao){
  __shared__ u16 Ks[2][4096];
  __shared__ u16 Vs[2][4096];
  const int tid = threadIdx.x;
  const int lane = tid & 63, wave = tid >> 6;
  const int il = lane & 31, hi = lane >> 5;
  int wg = ((blockIdx.x & 7) * 288) + (blockIdx.x >> 3);
  int h = wg / 288;
  int rem = wg - h*288;
  int b = rem / 9, qt = rem - (rem/9)*9;
  int bh = b*8 + h;
  int i0 = qt*128 + wave*32;

  // Q fragments (hoisted; q pre-scaled by SCALE*log2e in k_qkv)
  const u16* qp = qn + ((size_t)bh*QP_ + (i0 + il))*64 + hi*8;
  bf16x8 qf[4];
#pragma unroll
  for (int c=0;c<4;++c) qf[c] = *(const bf16x8*)(qp + 16*c);

  const u16* ksrc = kn2 + (size_t)bh*KVSZ_ + tid*8;
  const u16* vsrc = v2  + (size_t)bh*KVSZ_ + tid*8;

  // stage pair 0 (tiles 0,1) into buf 0
  gll16(ksrc,        &Ks[0][wave*512]);
  gll16(ksrc + 2048, &Ks[0][2048 + wave*512]);
  gll16(vsrc,        &Vs[0][wave*512]);
  gll16(vsrc + 2048, &Vs[0][2048 + wave*512]);

  f32x16 oA, oB, oS;
#pragma unroll
  for (int r=0;r<16;++r){ oA[r]=0.f; oB[r]=0.f; oS[r]=0.f; }

  const bf16x8 onesf = {0x3F80,0x3F80,0x3F80,0x3F80,0x3F80,0x3F80,0x3F80,0x3F80};

  const u16* bptr = br + ((size_t)(h*NT_)*BIP_ + (i0 + il))*32 + hi*16;
  bf16x8 cb0 = *(const bf16x8*)(bptr);
  bf16x8 cb1 = *(const bf16x8*)(bptr + 8);
  bf16x8 cb2 = *(const bf16x8*)(bptr + BT_);
  bf16x8 cb3 = *(const bf16x8*)(bptr + BT_ + 8);

  for (int t=0; t<16; ++t){
    const int cur = t & 1;
    __syncthreads();
    {
      const int base = (2*t+2)*2048;   // t=15 -> tiles 32,33 (pad tile valid)
      gll16(ksrc + base,        &Ks[cur^1][wave*512]);
      gll16(ksrc + base + 2048, &Ks[cur^1][2048 + wave*512]);
      gll16(vsrc + base,        &Vs[cur^1][wave*512]);
      gll16(vsrc + base + 2048, &Vs[cur^1][2048 + wave*512]);
    }
    TILE(cur, 0, cb0, cb1);
    cb0 = *(const bf16x8*)(bptr + 2*BT_);
    cb1 = *(const bf16x8*)(bptr + 2*BT_ + 8);
    TILE(cur, 2048, cb2, cb3);
    cb2 = *(const bf16x8*)(bptr + 3*BT_);
    cb3 = *(const bf16x8*)(bptr + 3*BT_ + 8);
    bptr += 2*BT_;
  }
  // tail: tile 32 in buf 0
  __syncthreads();
  TILE(0, 0, cb0, cb1);

  int i = i0 + il;
  if (i < N_){
    float inv = 1.f / oS[0];
    u16* op = ao + ((size_t)(b*N_ + i))*DIM_ + h*64;
#pragma unroll
    for (int q=0;q<4;++q)
#pragma unroll
      for (int pr=0;pr<2;++pr){
        int d0 = 8*q + 4*hi + 2*pr;
        u32 wA = cvtpk(oA[4*q+2*pr]*inv, oA[4*q+2*pr+1]*inv);
        u32 wB = cvtpk(oB[4*q+2*pr]*inv, oB[4*q+2*pr+1]*inv);
        *(u32*)(op + d0) = wA;
        *(u32*)(op + 32 + d0) = wB;
      }
  }
}

// ---------------- output projection (128x128 tile) ----------------
// grid 1028 = 257 x 4
__global__ __launch_bounds__(256)
void k_oproj(const u16* __restrict__ ab, const u16* __restrict__ wT, const float* __restrict__ bo,
             float* __restrict__ out){
  __shared__ u16 sh[16384];
  const int tid = threadIdx.x;
  const int lane = tid & 63, wid = tid >> 6;
  const int lg = lane >> 4, lr = lane & 15;
  const int wm = wid >> 1, wn = wid & 1;

  // bijective XCD swizzle (nwg=1028, q=128, r=4)
  int orig = blockIdx.x;
  int xcd = orig & 7, idx = orig >> 3;
  int wgid = (xcd < 4 ? xcd*129 : 516 + (xcd-4)*128) + idx;
  int mt = wgid >> 2, nt = wgid & 3;
  const int m0 = mt*128, n0 = nt*128;

  const int srow = tid >> 2;
  const int schunk = (tid & 3) ^ ((tid >> 3) & 3);
  const u16* asrc = ab + (size_t)(m0 + srow)*DIM_ + schunk*8;
  const u16* bsrc = wT + (size_t)(n0 + srow)*DIM_ + schunk*8;
  const int rsw = (lg ^ ((lr>>1)&3)) << 3;

  u16* As = sh;
  u16* Bs = sh + 8192;

  f32x4 acc[4][4];
#pragma unroll
  for (int m=0;m<4;++m)
#pragma unroll
    for (int n=0;n<4;++n) acc[m][n] = {0.f,0.f,0.f,0.f};

  gll16(asrc,            As + wid*512);
  gll16(asrc + 64*DIM_,  As + 2048 + wid*512);
  gll16(bsrc,            Bs + wid*512);
  gll16(bsrc + 64*DIM_,  Bs + 2048 + wid*512);

  for (int s=0; s<16; ++s){
    const int cur = s & 1;
    __syncthreads();
    if (s < 15){
      const int ko = (s+1)*32;
      gll16(asrc + ko,           As + (cur^1)*4096 + wid*512);
      gll16(asrc + ko + 64*DIM_, As + (cur^1)*4096 + 2048 + wid*512);
      gll16(bsrc + ko,           Bs + (cur^1)*4096 + wid*512);
      gll16(bsrc + ko + 64*DIM_, Bs + (cur^1)*4096 + 2048 + wid*512);
    }
    bf16x8 af[4], bf[4];
#pragma unroll
    for (int m=0;m<4;++m) af[m] = *(const bf16x8*)(As + cur*4096 + (64*wm+16*m+lr)*32 + rsw);
#pragma unroll
    for (int n=0;n<4;++n) bf[n] = *(const bf16x8*)(Bs + cur*4096 + (64*wn+16*n+lr)*32 + rsw);
    __builtin_amdgcn_s_setprio(1);
#pragma unroll
    for (int m=0;m<4;++m)
#pragma unroll
      for (int n=0;n<4;++n)
        acc[m][n] = __builtin_amdgcn_mfma_f32_16x16x32_bf16(af[m], bf[n], acc[m][n], 0, 0, 0);
    __builtin_amdgcn_s_setprio(0);
  }

  float bb[4];
#pragma unroll
  for (int n=0;n<4;++n) bb[n] = bo[n0 + 64*wn + 16*n + lr];
#pragma unroll
  for (int m=0;m<4;++m)
#pragma unroll
    for (int r=0;r<4;++r){
      int mg = m0 + 64*wm + 16*m + 4*lg + r;
      if (mg < M_){
#pragma unroll
        for (int n=0;n<4;++n)
          out[(size_t)mg*DIM_ + n0 + 64*wn + 16*n + lr] = acc[m][n][r] + bb[n];
      }
    }
}

// ---------------- launch ----------------
extern "C" void kernel_launch(void* const* d_in, const int* in_sizes, int n_in,
                              void* d_out, int out_size, void* d_ws, size_t ws_size,
                              hipStream_t stream) {
  const float* x     = (const float*)d_in[0];
  const float* w_qkv = (const float*)d_in[1];
  const float* g     = (const float*)d_in[2];
  const float* pe    = (const float*)d_in[3];
  const float* w_out = (const float*)d_in[4];
  const float* b_out = (const float*)d_in[5];
  const int*   bidx  = (const int*)d_in[6];
  float* out = (float*)d_out;

  char* ws = (char*)d_ws;
  u16* xb    = (u16*)(ws);                    // 33,587,200  (aliased: aob reuses after k_qkv)
  u16* wT    = (u16*)(ws + 33587200);         //  1,572,864
  u16* woT   = (u16*)(ws + 35160064);         //    524,288
  u16* qnb   = (u16*)(ws + 35684352);         // 37,748,736
  u16* kn2   = (u16*)(ws + 73433088);         // 35,651,584
  u16* v2    = (u16*)(ws + 109084672);        // 35,651,584
  u16* biasr = (u16*)(ws + 144736256);        // 20,054,016  (end 164,790,272)
  u16* aob   = xb;                            // alias: xb dead after k_qkv

  int n4 = (B_*N_*DIM_)/4;
  k_conv_x<<<(n4+255)/256, 256, 0, stream>>>(x, xb, n4);
  k_transpose<<<(1536*512+255)/256, 256, 0, stream>>>(w_qkv, wT, 512, 1536);
  k_transpose<<<(512*512+255)/256, 256, 0, stream>>>(w_out, woT, 512, 512);
  k_biasr<<<39168, 256, 0, stream>>>(bidx, pe, biasr);
  k_ztail<<<12096, 256, 0, stream>>>(qnb, kn2, v2);

  k_qkv<<<3084, 256, 0, stream>>>(xb, wT, g, qnb, kn2, v2);
  k_attn2<<<2304, 256, 0, stream>>>(qnb, kn2, v2, biasr, aob);
  k_oproj<<<1028, 256, 0, stream>>>(aob, woT, b_out, out);
}